// Round 1
// 26810.291 us; speedup vs baseline: 1.2391x; 1.2391x over previous
//
#include <hip/hip_runtime.h>
#include <stdint.h>

typedef __bf16 bf16x8 __attribute__((ext_vector_type(8)));
typedef short  s16x8  __attribute__((ext_vector_type(8)));
typedef float  f32x4  __attribute__((ext_vector_type(4)));

#define MFMA16(a, b, c) __builtin_amdgcn_mfma_f32_16x16x32_bf16((a), (b), (c), 0, 0, 0)

// ---------------- workspace layout (bytes) ----------------
#define OFF_X      0ull          // (T,64,512) bf16: xp, overwritten in-place by hs
#define OFF_QXBF   67108864ull   // (B,T,128) bf16 copy of q_x for emission
#define OFF_WIH    83886080ull
#define OFF_WHH    84410368ull
#define OFF_WXH    84934656ull
#define OFF_WICAT  85065728ull   // [Whm|Whl] interleaved 64-col blocks, N=256
#define OFF_W1CAT  85327872ull   // [Wg1|Wp1], N=1024
#define OFF_WG2    85590016ull
#define OFF_WP2    85721088ull
#define OFF_WMU    85852160ull
#define OFF_WLV    85884928ull
#define OFF_EW1    85917696ull
#define OFF_EW2    86048768ull
#define OFF_EW3    86573056ull
#define OFF_B1CAT  87097344ull   // fp32 [1024]
#define OFF_BICAT  87101440ull   // fp32 [256]
#define OFF_HC     87102464ull   // (64,512) bf16
#define OFF_XQ     87168000ull   // (64,128) bf16
#define OFF_U1     87184384ull   // (64,1024) bf16
#define OFF_PM     87315456ull   // (64,128) bf16
#define OFF_MU     87331840ull   // (64,128) bf16
#define OFF_XG     87348224ull   // (64,128) bf16
#define OFF_XPCNT  87364608ull   // int[1024]
#define OFF_RNNF   87368704ull   // int[16]
#define OFF_INFAF  87368768ull   // int[8]
#define OFF_INFBF  87368800ull   // int[8]
#define OFF_GENAF  87368832ull   // int[16]
#define OFF_GENBF  87368896ull   // int[32]

// ---------------- d_out offsets (floats) ----------------
#define QX_O  0ull
#define QMU_O 8388608ull
#define QLV_O 16777216ull
#define PX_O  25165824ull
#define PMU_O 33554432ull
#define PLV_O 41943040ull
#define Y_O   50331648ull

#define SMEM_SCAN 157696
#define SMEM_EMIS 133120

struct P {
  char* ws; float* out;
  const float *data, *eps_q, *eps_p;
  const float *Wih, *Whh, *bih, *bhh, *h0, *xq0, *x0;
  const float *Wxh, *bxh, *Whm, *bhm, *Whl, *bhl;
  const float *Wg1, *bg1, *Wg2, *bg2, *Wp1, *bp1, *Wp2, *bp2, *Wmu, *bmu, *Wlv, *blv;
  const float *eW1, *eb1, *eW2, *eb2, *eW3, *eb3;
};

__device__ __forceinline__ short f2bf(float f) {
  union { float f; uint32_t u; } v; v.f = f;
  uint32_t r = (v.u + 0x7FFFu + ((v.u >> 16) & 1u)) >> 16;
  return (short)(uint16_t)r;
}
__device__ __forceinline__ float bf2f(short s) {
  union { uint32_t u; float f; } v; v.u = ((uint32_t)(uint16_t)s) << 16;
  return v.f;
}
__device__ __forceinline__ bf16x8 ldfrag(const short* pp) { return *(const bf16x8*)pp; }
__device__ __forceinline__ bf16x8 cvt8p(const float* pp) {
  bf16x8 r;
#pragma unroll
  for (int i = 0; i < 8; ++i) r[i] = (__bf16)pp[i];
  return r;
}
__device__ __forceinline__ bf16x8 relu8(bf16x8 a) {
  s16x8 s = __builtin_bit_cast(s16x8, a);
#pragma unroll
  for (int i = 0; i < 8; ++i) s[i] = (s[i] < 0) ? (short)0 : s[i];
  return __builtin_bit_cast(bf16x8, s);
}

// -------- agent-scope (sc1, L2-bypass) communication primitives --------
// All cross-WG data goes through these: stores/loads are individually
// device-coherent via L3, so NO __threadfence (buffer_wbl2/buffer_inv) is
// needed anywhere in the scan kernel.
__device__ __forceinline__ void relfence() {  // drain own stores to coherence point
  asm volatile("s_waitcnt vmcnt(0)" ::: "memory");
}
__device__ __forceinline__ void st_sc16(short* pp, short v) {
  __hip_atomic_store(pp, v, __ATOMIC_RELAXED, __HIP_MEMORY_SCOPE_AGENT);
}
__device__ __forceinline__ short ld_sc16(const short* pp) {
  return __hip_atomic_load((short*)pp, __ATOMIC_RELAXED, __HIP_MEMORY_SCOPE_AGENT);
}
__device__ __forceinline__ unsigned long long ld_sc64(const void* pp) {
  return __hip_atomic_load((unsigned long long*)pp, __ATOMIC_RELAXED, __HIP_MEMORY_SCOPE_AGENT);
}
__device__ __forceinline__ bf16x8 ldfrag_sc(const short* pp) {
  union { unsigned long long q[2]; bf16x8 v; } u;
  u.q[0] = ld_sc64(pp);
  u.q[1] = ld_sc64(pp + 4);
  return u.v;
}
__device__ __forceinline__ int ldflag(int* pp) {
  return __hip_atomic_load(pp, __ATOMIC_RELAXED, __HIP_MEMORY_SCOPE_AGENT);
}
__device__ __forceinline__ void stflag(int* pp, int v) {
  __hip_atomic_store(pp, v, __ATOMIC_RELAXED, __HIP_MEMORY_SCOPE_AGENT);
}
// wave0 polls flags[0..n) >= target; then block-wide. Data reads after this
// must use ldfrag_sc/ld_sc16 (they bypass stale L1/L2), so no fence here.
__device__ __forceinline__ void waitf(int* f, int n, int target) {
  if (threadIdx.x < 64) {
    const int ln = threadIdx.x;
    while (1) {
      int v = (ln < n) ? ldflag(f + ln) : target;
      if (__all(v >= target)) break;
      __builtin_amdgcn_s_sleep(1);
    }
  }
  __syncthreads();
}
// publish: producer's sc1 data stores are drained (vmcnt(0)) by every thread,
// then the flag (also sc1) is stored -> any observer of the flag sees the data.
__device__ __forceinline__ void pubf(int* f, int val) {
  relfence();
  __syncthreads();
  if (threadIdx.x == 0) stflag(f, val);
}
__device__ __forceinline__ void cpy16(void* dst, const void* src, int n16) {
  float4* d = (float4*)dst; const float4* s = (const float4*)src;
  for (int i = threadIdx.x; i < n16; i += 256) d[i] = s[i];
}

// pack W (K x N, row-major fp32) into MFMA-B fragment order:
// dst[((nt*KT+kt)*64+lane)*8+j] = W[kt*32+(lane>>4)*8+j][nt*16+(lane&15)]
__device__ __forceinline__ void pack_w(short* dst, const float* src, int KT, int N, int idx) {
  int tile = idx >> 9, rem = idx & 511;
  int lane = rem >> 3, j = rem & 7;
  int nt = tile / KT, kt = tile - nt * KT;
  int k = kt * 32 + ((lane >> 4) << 3) + j, n = (nt << 4) + (lane & 15);
  dst[idx] = f2bf(src[(int64_t)k * N + n]);
}

__global__ void __launch_bounds__(256) k_prep(P p) {
  char* ws = p.ws;
  const int64_t total = 1608032;
  for (int64_t i = (int64_t)blockIdx.x * 256 + threadIdx.x; i < total;
       i += (int64_t)gridDim.x * 256) {
    int64_t r = i;
    if (r < 262144) { pack_w((short*)(ws + OFF_WIH), p.Wih, 16, 512, (int)r); continue; }
    r -= 262144;
    if (r < 262144) { pack_w((short*)(ws + OFF_WHH), p.Whh, 16, 512, (int)r); continue; }
    r -= 262144;
    if (r < 65536) { pack_w((short*)(ws + OFF_WXH), p.Wxh, 4, 512, (int)r); continue; }
    r -= 65536;
    if (r < 131072) {  // Wicat: [mu0-63|lv0-63|mu64-127|lv64-127], KT=16
      int idx = (int)r;
      int tile = idx >> 9, rem = idx & 511, lane = rem >> 3, jj = rem & 7;
      int nt = tile >> 4, kt = tile & 15;
      int k = kt * 32 + ((lane >> 4) << 3) + jj, ccol = (nt << 4) + (lane & 15);
      int pair = ccol >> 7, within = ccol & 127, sub = within >> 6;
      int col = (within & 63) + (pair << 6);
      const float* s = sub ? p.Whl : p.Whm;
      ((short*)(ws + OFF_WICAT))[idx] = f2bf(s[(int64_t)k * 128 + col]);
      continue;
    }
    r -= 131072;
    if (r < 131072) {  // W1cat = [Wg1|Wp1], KT=4, N=1024
      int idx = (int)r;
      int tile = idx >> 9, rem = idx & 511, lane = rem >> 3, jj = rem & 7;
      int nt = tile >> 2, kt = tile & 3;
      int k = kt * 32 + ((lane >> 4) << 3) + jj, ccol = (nt << 4) + (lane & 15);
      const float* s = (ccol < 512) ? p.Wg1 : p.Wp1;
      ((short*)(ws + OFF_W1CAT))[idx] = f2bf(s[(int64_t)k * 512 + (ccol & 511)]);
      continue;
    }
    r -= 131072;
    if (r < 65536) { pack_w((short*)(ws + OFF_WG2), p.Wg2, 16, 128, (int)r); continue; }
    r -= 65536;
    if (r < 65536) { pack_w((short*)(ws + OFF_WP2), p.Wp2, 16, 128, (int)r); continue; }
    r -= 65536;
    if (r < 16384) { pack_w((short*)(ws + OFF_WMU), p.Wmu, 4, 128, (int)r); continue; }
    r -= 16384;
    if (r < 16384) { pack_w((short*)(ws + OFF_WLV), p.Wlv, 4, 128, (int)r); continue; }
    r -= 16384;
    if (r < 65536) { pack_w((short*)(ws + OFF_EW1), p.eW1, 4, 512, (int)r); continue; }
    r -= 65536;
    if (r < 262144) { pack_w((short*)(ws + OFF_EW2), p.eW2, 16, 512, (int)r); continue; }
    r -= 262144;
    if (r < 262144) { pack_w((short*)(ws + OFF_EW3), p.eW3, 16, 512, (int)r); continue; }
    r -= 262144;
    if (r < 1024) { ((float*)(ws + OFF_B1CAT))[r] = (r < 512) ? p.bg1[r] : p.bp1[r - 512]; continue; }
    r -= 1024;
    if (r < 256) {
      int ccol = (int)r; int pair = ccol >> 7, within = ccol & 127, sub = within >> 6;
      int col = (within & 63) + (pair << 6);
      ((float*)(ws + OFF_BICAT))[ccol] = sub ? p.bhl[col] : p.bhm[col];
      continue;
    }
    r -= 256;
    ((int*)(ws + OFF_XPCNT))[r] = 0;  // r < 1120: all flags/counters
  }
}

// =====================================================================
// persistent scan kernel: 128 WGs.
//   [0,64):  xproj crew (x_proj GEMM, progress-counted)
//   [64,80): RNN crew (4 batch-groups x 4 col-slices) -> re-role as inf crew
//   [80,128): gen crew (4 groups x (4 A-WGs + 8 B-WGs)), 2 hops/step
// All cross-WG traffic uses agent-scope (sc1) atomics; zero threadfences.
// =====================================================================
__global__ void __launch_bounds__(256) k_scan(P p) {
  extern __shared__ char smem[];
  char* ws = p.ws;
  const int tid = threadIdx.x;
  const int lane = tid & 63, w = tid >> 6;
  const int l16 = lane & 15, quad = lane >> 4;
  const int wg = blockIdx.x;

  short* Xb   = (short*)(ws + OFF_X);
  short* qxbf = (short*)(ws + OFF_QXBF);
  int* xp_cnt = (int*)(ws + OFF_XPCNT);

  if (wg < 64) {
    // ---------------- xproj crew ----------------
    const int s = wg & 7, t0 = wg >> 3;
    const short* wih = (const short*)(ws + OFF_WIH);
    for (int tt = 0; tt < 128; ++tt) {
      const int t = t0 + (tt << 3);
      const int tsrc = 1023 - t;
      const float* arow = p.data + ((size_t)(w * 16 + l16) * 1024 + tsrc) * 512 + quad * 8;
      f32x4 acc[4] = {};
      for (int kt = 0; kt < 16; ++kt) {
        bf16x8 af = cvt8p(arow + kt * 32);
#pragma unroll
        for (int i = 0; i < 4; ++i) {
          const int nt = s * 4 + i;
          bf16x8 bw = ldfrag(wih + ((size_t)(nt * 16 + kt) * 64 + lane) * 8);
          acc[i] = MFMA16(af, bw, acc[i]);
        }
      }
      short* xrow = Xb + (size_t)t * 32768;
#pragma unroll
      for (int i = 0; i < 4; ++i) {
        const int col = (s * 4 + i) * 16 + l16;
        const float bias = p.bih[col] + p.bhh[col];
#pragma unroll
        for (int r = 0; r < 4; ++r) {
          const int row = w * 16 + quad * 4 + r;
          st_sc16(xrow + (size_t)row * 512 + col, f2bf(acc[i][r] + bias));
        }
      }
      relfence();
      __syncthreads();
      if (tid == 0) atomicAdd(xp_cnt + t, 1);
    }
    return;
  }

  if (wg < 80) {
    // ---------------- RNN crew ----------------
    const int id = wg - 64, g = id >> 2, c = id & 3;
    short* lds = (short*)smem;
    cpy16(smem, ws + OFF_WHH + (size_t)c * 131072, 8192);  // 8 nt x 16 kt slice
    __syncthreads();
    int* rf = (int*)(ws + OFF_RNNF) + g * 4;
    for (int t = 0; t < 1024; ++t) {
      if (tid < 64) {
        while (1) {
          int ok = 1;
          if (tid < 4) { if (t > 0) ok = (ldflag(rf + tid) >= t); }
          else if (tid == 4) ok = (ldflag(xp_cnt + t) >= 8);
          if (__all(ok)) break;
          __builtin_amdgcn_s_sleep(1);
        }
      }
      __syncthreads();
      f32x4 acc[2] = {};
      const short* hrow = Xb + (size_t)(t > 0 ? t - 1 : 0) * 32768 + (size_t)(g * 16 + l16) * 512 + quad * 8;
      const float* h0p = p.h0 + quad * 8;
      for (int kt = 0; kt < 16; ++kt) {
        bf16x8 af = (t == 0) ? cvt8p(h0p + kt * 32) : ldfrag_sc(hrow + kt * 32);
#pragma unroll
        for (int i = 0; i < 2; ++i) {
          const int ntl = w * 2 + i;
          bf16x8 bw = ldfrag(lds + ((size_t)(ntl * 16 + kt) * 64 + lane) * 8);
          acc[i] = MFMA16(af, bw, acc[i]);
        }
      }
      short* xrow = Xb + (size_t)t * 32768;
#pragma unroll
      for (int i = 0; i < 2; ++i) {
        const int col = c * 128 + (w * 2 + i) * 16 + l16;
#pragma unroll
        for (int r = 0; r < 4; ++r) {
          const int row = g * 16 + quad * 4 + r;
          const size_t o = (size_t)row * 512 + col;
          float h = acc[i][r] + bf2f(ld_sc16(xrow + o));
          st_sc16(xrow + o, f2bf(h > 0.f ? h : 0.f));
        }
      }
      pubf(rf + c, t + 1);
    }
    // ---------------- re-role: inf crew ----------------
    waitf(rf, 4, 1024);  // whole group's hs complete
    const int g2 = g, r2 = c;
    short* hcb = (short*)(ws + OFF_HC);
    short* xqb = (short*)(ws + OFF_XQ);
    int* fa = (int*)(ws + OFF_INFAF) + g2 * 2;
    int* fb = (int*)(ws + OFF_INFBF) + g2 * 2;
    if (r2 < 2) {
      // stage A: h_c = 0.5*(tanh(x_prev@Wxh+bxh) + rnn_out[t]); 256-col slice
      cpy16(smem, ws + OFF_WXH + (size_t)r2 * 65536, 4096);
      short* lda = (short*)smem;
      __syncthreads();
      for (int t = 0; t < 1024; ++t) {
        if (t > 0) waitf(fb, 2, t);
        f32x4 acc[4] = {};
        const short* xrow = xqb + (size_t)(g2 * 16 + l16) * 128 + quad * 8;
        const float* xq0p = p.xq0 + quad * 8;
        for (int kt = 0; kt < 4; ++kt) {
          bf16x8 af = (t == 0) ? cvt8p(xq0p + kt * 32) : ldfrag_sc(xrow + kt * 32);
#pragma unroll
          for (int i = 0; i < 4; ++i) {
            const int ntl = w * 4 + i;
            bf16x8 bw = ldfrag(lda + ((size_t)(ntl * 4 + kt) * 64 + lane) * 8);
            acc[i] = MFMA16(af, bw, acc[i]);
          }
        }
        const short* rsrc = Xb + (size_t)(1023 - t) * 32768;
#pragma unroll
        for (int i = 0; i < 4; ++i) {
          const int ng = r2 * 256 + (w * 4 + i) * 16 + l16;
          const float bx = p.bxh[ng];
#pragma unroll
          for (int r = 0; r < 4; ++r) {
            const int row = g2 * 16 + quad * 4 + r;
            const float u = acc[i][r] + bx;
            const float e = __expf(2.f * u);
            const float th = 1.f - 2.f / (e + 1.f);
            const float hc = 0.5f * (th + bf2f(ld_sc16(rsrc + (size_t)row * 512 + ng)));
            st_sc16(hcb + (size_t)row * 512 + ng, f2bf(hc));
          }
        }
        pubf(fa + r2, t + 1);
      }
    } else {
      // stage B: [mu|lv] slice from h_c; sample x_t; write q_* outputs
      const int j = r2 - 2;
      cpy16(smem, ws + OFF_WICAT + (size_t)j * 131072, 8192);
      short* ldb = (short*)smem;
      float* scr = (float*)(smem + 131072);  // [2][16][64]
      const float* bicat = (const float*)(ws + OFF_BICAT);
      __syncthreads();
      for (int t = 0; t < 1024; ++t) {
        waitf(fa, 2, t + 1);
        f32x4 acc[2] = {};
        const short* hrow2 = hcb + (size_t)(g2 * 16 + l16) * 512 + quad * 8;
        for (int kt = 0; kt < 16; ++kt) {
          bf16x8 af = ldfrag_sc(hrow2 + kt * 32);
#pragma unroll
          for (int i = 0; i < 2; ++i) {
            const int ntl = w * 2 + i;
            bf16x8 bw = ldfrag(ldb + ((size_t)(ntl * 16 + kt) * 64 + lane) * 8);
            acc[i] = MFMA16(af, bw, acc[i]);
          }
        }
#pragma unroll
        for (int i = 0; i < 2; ++i) {
          const int catcol = (j * 8 + w * 2 + i) * 16 + l16;
          const int pair = catcol >> 7, within = catcol & 127, sub = within >> 6;
          const int col = (within & 63) + (pair << 6);
          const float bias = bicat[catcol];
          float* dbase = p.out + (sub ? QLV_O : QMU_O);
#pragma unroll
          for (int r = 0; r < 4; ++r) {
            const int row = quad * 4 + r, b = g2 * 16 + row;
            const float v = acc[i][r] + bias;
            dbase[(size_t)b * 131072 + (size_t)t * 128 + col] = v;
            scr[(sub * 16 + row) * 64 + (col & 63)] = v;
          }
        }
        __syncthreads();
        for (int i2 = tid; i2 < 1024; i2 += 256) {
          const int row = i2 >> 6, cl = i2 & 63;
          const int col = j * 64 + cl, b = g2 * 16 + row;
          const float m = scr[row * 64 + cl], l = scr[1024 + row * 64 + cl];
          const float xv = m + p.eps_q[((size_t)t * 64 + b) * 128 + col] * __expf(0.5f * l);
          p.out[QX_O + (size_t)b * 131072 + (size_t)t * 128 + col] = xv;
          qxbf[((size_t)b * 1024 + t) * 128 + col] = f2bf(xv);
          st_sc16(xqb + (size_t)b * 128 + col, f2bf(xv));
        }
        pubf(fb + j, t + 1);
      }
    }
    return;
  }

  // ---------------- gen crew ----------------
  {
    const int id = wg - 80, g3 = id / 12, r3 = id % 12;
    short* u1b = (short*)(ws + OFF_U1);
    short* pmb = (short*)(ws + OFF_PM);
    short* mub = (short*)(ws + OFF_MU);
    short* xgb = (short*)(ws + OFF_XG);
    int* fga = (int*)(ws + OFF_GENAF) + g3 * 4;
    int* fgb = (int*)(ws + OFF_GENBF) + g3 * 8;
    if (r3 < 4) {
      // stage A: lv_{t-1}(full, redundant) -> x_{t-1} -> u1_t slice
      short* ldsW1 = (short*)smem;
      short* ldsLv = (short*)(smem + 65536);
      short* xl = (short*)(smem + 98304);  // [16][128] bf16, local x_{t-1}
      cpy16(smem, ws + OFF_W1CAT + (size_t)r3 * 65536, 4096);
      cpy16(smem + 65536, ws + OFF_WLV, 2048);
      const float* b1cat = (const float*)(ws + OFF_B1CAT);
      __syncthreads();
      for (int t = 0; t <= 1024; ++t) {
        if (t == 0) {
          for (int i2 = tid; i2 < 2048; i2 += 256) xl[i2] = f2bf(p.x0[i2 & 127]);
          __syncthreads();
        } else {
          waitf(fgb, 8, t);
          f32x4 acl[2] = {};
          const short* pmrow = pmb + (size_t)(g3 * 16 + l16) * 128 + quad * 8;
          for (int kt = 0; kt < 4; ++kt) {
            bf16x8 af = relu8(ldfrag_sc(pmrow + kt * 32));
#pragma unroll
            for (int i = 0; i < 2; ++i) {
              const int ntl = w * 2 + i;
              bf16x8 bw = ldfrag(ldsLv + ((size_t)(ntl * 4 + kt) * 64 + lane) * 8);
              acl[i] = MFMA16(af, bw, acl[i]);
            }
          }
#pragma unroll
          for (int i = 0; i < 2; ++i) {
            const int col = (w * 2 + i) * 16 + l16;
            const float bl = p.blv[col];
#pragma unroll
            for (int r = 0; r < 4; ++r) {
              const int row = quad * 4 + r, b = g3 * 16 + row;
              const float lv = acl[i][r] + bl;
              const float mu = bf2f(ld_sc16(mub + (size_t)(g3 * 16 + row) * 128 + col));
              const float xv = mu + p.eps_p[((size_t)(t - 1) * 64 + b) * 128 + col] * __expf(0.5f * lv);
              if (w == r3) {
                p.out[PLV_O + (size_t)b * 131072 + (size_t)(t - 1) * 128 + col] = lv;
                p.out[PX_O + (size_t)b * 131072 + (size_t)(t - 1) * 128 + col] = xv;
              }
              xl[row * 128 + col] = f2bf(xv);
            }
          }
          __syncthreads();
        }
        if (t == 1024) break;
        f32x4 acc[4] = {};
        const short* xrow = xl + l16 * 128 + quad * 8;
        for (int kt = 0; kt < 4; ++kt) {
          bf16x8 af = ldfrag(xrow + kt * 32);
#pragma unroll
          for (int i = 0; i < 4; ++i) {
            const int ntl = w * 4 + i;
            bf16x8 bw = ldfrag(ldsW1 + ((size_t)(ntl * 4 + kt) * 64 + lane) * 8);
            acc[i] = MFMA16(af, bw, acc[i]);
          }
        }
#pragma unroll
        for (int i = 0; i < 4; ++i) {
          const int c1 = (r3 * 16 + w * 4 + i) * 16 + l16;
          const float bias = b1cat[c1];
#pragma unroll
          for (int r = 0; r < 4; ++r) {
            const int row = quad * 4 + r;
            const float u = acc[i][r] + bias;
            st_sc16(u1b + (size_t)(g3 * 16 + row) * 1024 + c1, f2bf(u > 0.f ? u : 0.f));
          }
        }
        if (r3 == 0)
          for (int i2 = tid; i2 < 2048; i2 += 256) st_sc16(xgb + (size_t)g3 * 2048 + i2, xl[i2]);
        pubf(fga + r3, t + 1);
      }
    } else {
      // stage B: pm full (redundant), gate/xmu/mu 16-col slice
      const int j = r3 - 4;
      short* ldsP2 = (short*)smem;
      short* ldsG2 = (short*)(smem + 131072);
      short* ldsMu = (short*)(smem + 147456);
      short* spm = (short*)(smem + 151552);  // [16][128] bf16
      float* sg  = (float*)(smem + 155648);  // [16][16]
      float* sxm = (float*)(smem + 156672);  // [16][16]
      cpy16(smem, ws + OFF_WP2, 8192);
      cpy16(smem + 131072, ws + OFF_WG2 + (size_t)j * 16384, 1024);
      cpy16(smem + 147456, ws + OFF_WMU + (size_t)j * 4096, 256);
      __syncthreads();
      for (int t = 0; t < 1024; ++t) {
        waitf(fga, 4, t + 1);
        f32x4 acc[2] = {};
        const short* u1p = u1b + (size_t)(g3 * 16 + l16) * 1024 + 512 + quad * 8;
        for (int kt = 0; kt < 16; ++kt) {
          bf16x8 af = ldfrag_sc(u1p + kt * 32);
#pragma unroll
          for (int i = 0; i < 2; ++i) {
            const int ntl = w * 2 + i;
            bf16x8 bw = ldfrag(ldsP2 + ((size_t)(ntl * 16 + kt) * 64 + lane) * 8);
            acc[i] = MFMA16(af, bw, acc[i]);
          }
        }
#pragma unroll
        for (int i = 0; i < 2; ++i) {
          const int col = (w * 2 + i) * 16 + l16;
          const float bias = p.bp2[col];
#pragma unroll
          for (int r = 0; r < 4; ++r) spm[(quad * 4 + r) * 128 + col] = f2bf(acc[i][r] + bias);
        }
        if (w == 0) {
          f32x4 ga = {};
          const short* u1g = u1b + (size_t)(g3 * 16 + l16) * 1024 + quad * 8;
          for (int kt = 0; kt < 16; ++kt) {
            bf16x8 af = ldfrag_sc(u1g + kt * 32);
            bf16x8 bw = ldfrag(ldsG2 + ((size_t)kt * 64 + lane) * 8);
            ga = MFMA16(af, bw, ga);
          }
#pragma unroll
          for (int r = 0; r < 4; ++r) sg[(quad * 4 + r) * 16 + l16] = ga[r];
        } else if (w == 1) {
          f32x4 xm = {};
          const short* xg = xgb + (size_t)(g3 * 16 + l16) * 128 + quad * 8;
          for (int kt = 0; kt < 4; ++kt) {
            bf16x8 af = ldfrag_sc(xg + kt * 32);
            bf16x8 bw = ldfrag(ldsMu + ((size_t)kt * 64 + lane) * 8);
            xm = MFMA16(af, bw, xm);
          }
#pragma unroll
          for (int r = 0; r < 4; ++r) sxm[(quad * 4 + r) * 16 + l16] = xm[r];
        }
        __syncthreads();
        {
          const int row = tid >> 4, cl = tid & 15;
          const int col = j * 16 + cl, b = g3 * 16 + row;
          const float gv = 1.f / (1.f + __expf(-(sg[row * 16 + cl] + p.bg2[col])));
          const float xmv = sxm[row * 16 + cl] + p.bmu[col];
          const float pmv = bf2f(spm[row * 128 + col]);
          const float mu = (1.f - gv) * xmv + gv * pmv;
          st_sc16(mub + (size_t)b * 128 + col, f2bf(mu));
          p.out[PMU_O + (size_t)b * 131072 + (size_t)t * 128 + col] = mu;
        }
        if (j == 0)
          for (int i2 = tid; i2 < 2048; i2 += 256) st_sc16(pmb + (size_t)g3 * 2048 + i2, spm[i2]);
        pubf(fgb + j, t + 1);
      }
    }
    return;
  }
}

// =====================================================================
// fused emission MLP: y = sigmoid(relu(relu(qx@W1+b1)@W2+b2)@W3+b3)
// =====================================================================
__global__ void __launch_bounds__(256) k_emis(P p) {
  extern __shared__ char smem[];
  short* h1 = (short*)smem;            // [64][520] bf16 (pad 8 -> 2-way banks)
  short* h2 = (short*)(smem + 66560);  // [64][520]
  const int tid = threadIdx.x, lane = tid & 63, w = tid >> 6;
  const int l16 = lane & 15, quad = lane >> 4;
  const size_t m0 = (size_t)blockIdx.x * 64;
  const short* qx  = (const short*)(p.ws + OFF_QXBF);
  const short* ew1 = (const short*)(p.ws + OFF_EW1);
  const short* ew2 = (const short*)(p.ws + OFF_EW2);
  const short* ew3 = (const short*)(p.ws + OFF_EW3);
  for (int nc = 0; nc < 2; ++nc) {
    f32x4 acc[4][4] = {};
    for (int kt = 0; kt < 4; ++kt) {
      bf16x8 bw[4];
#pragma unroll
      for (int i = 0; i < 4; ++i) {
        const int nt = w * 8 + nc * 4 + i;
        bw[i] = ldfrag(ew1 + ((size_t)(nt * 4 + kt) * 64 + lane) * 8);
      }
#pragma unroll
      for (int mt = 0; mt < 4; ++mt) {
        bf16x8 af = ldfrag(qx + (m0 + mt * 16 + l16) * 128 + kt * 32 + quad * 8);
#pragma unroll
        for (int i = 0; i < 4; ++i) acc[mt][i] = MFMA16(af, bw[i], acc[mt][i]);
      }
    }
#pragma unroll
    for (int mt = 0; mt < 4; ++mt)
#pragma unroll
      for (int i = 0; i < 4; ++i) {
        const int col = (w * 8 + nc * 4 + i) * 16 + l16;
        const float bias = p.eb1[col];
#pragma unroll
        for (int r = 0; r < 4; ++r) {
          const float v = acc[mt][i][r] + bias;
          h1[(mt * 16 + quad * 4 + r) * 520 + col] = f2bf(v > 0.f ? v : 0.f);
        }
      }
  }
  __syncthreads();
  for (int nc = 0; nc < 2; ++nc) {
    f32x4 acc[4][4] = {};
    for (int kt = 0; kt < 16; ++kt) {
      bf16x8 bw[4];
#pragma unroll
      for (int i = 0; i < 4; ++i) {
        const int nt = w * 8 + nc * 4 + i;
        bw[i] = ldfrag(ew2 + ((size_t)(nt * 16 + kt) * 64 + lane) * 8);
      }
#pragma unroll
      for (int mt = 0; mt < 4; ++mt) {
        bf16x8 af = ldfrag(h1 + (mt * 16 + l16) * 520 + kt * 32 + quad * 8);
#pragma unroll
        for (int i = 0; i < 4; ++i) acc[mt][i] = MFMA16(af, bw[i], acc[mt][i]);
      }
    }
#pragma unroll
    for (int mt = 0; mt < 4; ++mt)
#pragma unroll
      for (int i = 0; i < 4; ++i) {
        const int col = (w * 8 + nc * 4 + i) * 16 + l16;
        const float bias = p.eb2[col];
#pragma unroll
        for (int r = 0; r < 4; ++r) {
          const float v = acc[mt][i][r] + bias;
          h2[(mt * 16 + quad * 4 + r) * 520 + col] = f2bf(v > 0.f ? v : 0.f);
        }
      }
  }
  __syncthreads();
  for (int nc = 0; nc < 2; ++nc) {
    f32x4 acc[4][4] = {};
    for (int kt = 0; kt < 16; ++kt) {
      bf16x8 bw[4];
#pragma unroll
      for (int i = 0; i < 4; ++i) {
        const int nt = w * 8 + nc * 4 + i;
        bw[i] = ldfrag(ew3 + ((size_t)(nt * 16 + kt) * 64 + lane) * 8);
      }
#pragma unroll
      for (int mt = 0; mt < 4; ++mt) {
        bf16x8 af = ldfrag(h2 + (mt * 16 + l16) * 520 + kt * 32 + quad * 8);
#pragma unroll
        for (int i = 0; i < 4; ++i) acc[mt][i] = MFMA16(af, bw[i], acc[mt][i]);
      }
    }
#pragma unroll
    for (int mt = 0; mt < 4; ++mt)
#pragma unroll
      for (int i = 0; i < 4; ++i) {
        const int col = (w * 8 + nc * 4 + i) * 16 + l16;
        const float bias = p.eb3[col];
#pragma unroll
        for (int r = 0; r < 4; ++r) {
          const size_t m = m0 + mt * 16 + quad * 4 + r;
          const size_t b = m >> 10, tt2 = m & 1023;
          const float v = acc[mt][i][r] + bias;
          p.out[Y_O + (b << 19) + tt2 * 512 + col] = 1.f / (1.f + __expf(-v));
        }
      }
  }
}

extern "C" void kernel_launch(void* const* d_in, const int* in_sizes, int n_in,
                              void* d_out, int out_size, void* d_ws, size_t ws_size,
                              hipStream_t stream) {
  (void)in_sizes; (void)n_in; (void)out_size; (void)ws_size;
  P p;
  p.ws = (char*)d_ws; p.out = (float*)d_out;
  p.data = (const float*)d_in[0];
  p.eps_q = (const float*)d_in[1];
  p.eps_p = (const float*)d_in[2];
  p.Wih = (const float*)d_in[3]; p.Whh = (const float*)d_in[4];
  p.bih = (const float*)d_in[5]; p.bhh = (const float*)d_in[6];
  p.h0 = (const float*)d_in[7]; p.xq0 = (const float*)d_in[8]; p.x0 = (const float*)d_in[9];
  p.Wxh = (const float*)d_in[10]; p.bxh = (const float*)d_in[11];
  p.Whm = (const float*)d_in[12]; p.bhm = (const float*)d_in[13];
  p.Whl = (const float*)d_in[14]; p.bhl = (const float*)d_in[15];
  p.Wg1 = (const float*)d_in[16]; p.bg1 = (const float*)d_in[17];
  p.Wg2 = (const float*)d_in[18]; p.bg2 = (const float*)d_in[19];
  p.Wp1 = (const float*)d_in[20]; p.bp1 = (const float*)d_in[21];
  p.Wp2 = (const float*)d_in[22]; p.bp2 = (const float*)d_in[23];
  p.Wmu = (const float*)d_in[24]; p.bmu = (const float*)d_in[25];
  p.Wlv = (const float*)d_in[26]; p.blv = (const float*)d_in[27];
  p.eW1 = (const float*)d_in[28]; p.eb1 = (const float*)d_in[29];
  p.eW2 = (const float*)d_in[30]; p.eb2 = (const float*)d_in[31];
  p.eW3 = (const float*)d_in[32]; p.eb3 = (const float*)d_in[33];

  hipFuncSetAttribute(reinterpret_cast<const void*>(k_scan),
                      hipFuncAttributeMaxDynamicSharedMemorySize, SMEM_SCAN);
  hipFuncSetAttribute(reinterpret_cast<const void*>(k_emis),
                      hipFuncAttributeMaxDynamicSharedMemorySize, SMEM_EMIS);

  k_prep<<<dim3(2048), dim3(256), 0, stream>>>(p);
  k_scan<<<dim3(128), dim3(256), SMEM_SCAN, stream>>>(p);
  k_emis<<<dim3(1024), dim3(256), SMEM_EMIS, stream>>>(p);
}

// Round 2
// 15237.271 us; speedup vs baseline: 2.1802x; 1.7595x over previous
//
#include <hip/hip_runtime.h>
#include <stdint.h>

typedef __bf16 bf16x8 __attribute__((ext_vector_type(8)));
typedef short  s16x8  __attribute__((ext_vector_type(8)));
typedef float  f32x4  __attribute__((ext_vector_type(4)));

#define MFMA16(a, b, c) __builtin_amdgcn_mfma_f32_16x16x32_bf16((a), (b), (c), 0, 0, 0)

// ---------------- workspace layout (bytes) ----------------
#define OFF_X      0ull          // (T,64,512) bf16: xp, overwritten in-place by hs
#define OFF_QXBF   67108864ull   // (B,T,128) bf16 copy of q_x for emission
#define OFF_WIH    83886080ull
#define OFF_WHH    84410368ull
#define OFF_WXH    84934656ull
#define OFF_WICAT  85065728ull   // [Whm|Whl] interleaved 64-col blocks, N=256
#define OFF_W1CAT  85327872ull   // [Wg1|Wp1], N=1024
#define OFF_WG2    85590016ull
#define OFF_WP2    85721088ull
#define OFF_WMU    85852160ull
#define OFF_WLV    85884928ull
#define OFF_EW1    85917696ull
#define OFF_EW2    86048768ull
#define OFF_EW3    86573056ull
#define OFF_B1CAT  87097344ull   // fp32 [1024]
#define OFF_BICAT  87101440ull   // fp32 [256]
#define OFF_HC     87102464ull   // (64,512) bf16
#define OFF_XQ     87168000ull   // (64,128) bf16
#define OFF_U1     87184384ull   // (64,1024) bf16
#define OFF_PM     87315456ull   // (64,128) bf16
#define OFF_MU     87331840ull   // (64,128) bf16
#define OFF_XG     87348224ull   // (64,128) bf16
#define OFF_XPCNT  87364608ull   // int[1024]
#define OFF_RNNF   87368704ull   // int[16]
#define OFF_INFAF  87368768ull   // int[8]
#define OFF_INFBF  87368800ull   // int[8]
#define OFF_GENAF  87368832ull   // int[16]
#define OFF_GENBF  87368896ull   // int[32]

// ---------------- d_out offsets (floats) ----------------
#define QX_O  0ull
#define QMU_O 8388608ull
#define QLV_O 16777216ull
#define PX_O  25165824ull
#define PMU_O 33554432ull
#define PLV_O 41943040ull
#define Y_O   50331648ull

#define SMEM_SCAN 8192
#define SMEM_EMIS 133120

struct P {
  char* ws; float* out;
  const float *data, *eps_q, *eps_p;
  const float *Wih, *Whh, *bih, *bhh, *h0, *xq0, *x0;
  const float *Wxh, *bxh, *Whm, *bhm, *Whl, *bhl;
  const float *Wg1, *bg1, *Wg2, *bg2, *Wp1, *bp1, *Wp2, *bp2, *Wmu, *bmu, *Wlv, *blv;
  const float *eW1, *eb1, *eW2, *eb2, *eW3, *eb3;
};

__device__ __forceinline__ short f2bf(float f) {
  union { float f; uint32_t u; } v; v.f = f;
  uint32_t r = (v.u + 0x7FFFu + ((v.u >> 16) & 1u)) >> 16;
  return (short)(uint16_t)r;
}
__device__ __forceinline__ float bf2f(short s) {
  union { uint32_t u; float f; } v; v.u = ((uint32_t)(uint16_t)s) << 16;
  return v.f;
}
__device__ __forceinline__ bf16x8 ldfrag(const short* pp) { return *(const bf16x8*)pp; }
__device__ __forceinline__ bf16x8 cvt8p(const float* pp) {
  bf16x8 r;
#pragma unroll
  for (int i = 0; i < 8; ++i) r[i] = (__bf16)pp[i];
  return r;
}
__device__ __forceinline__ bf16x8 relu8(bf16x8 a) {
  s16x8 s = __builtin_bit_cast(s16x8, a);
#pragma unroll
  for (int i = 0; i < 8; ++i) s[i] = (s[i] < 0) ? (short)0 : s[i];
  return __builtin_bit_cast(bf16x8, s);
}

// -------- agent-scope (sc1, L2-bypass) communication primitives --------
__device__ __forceinline__ void relfence() {  // drain own stores to coherence point
  asm volatile("s_waitcnt vmcnt(0)" ::: "memory");
}
__device__ __forceinline__ void st_sc16(short* pp, short v) {
  __hip_atomic_store(pp, v, __ATOMIC_RELAXED, __HIP_MEMORY_SCOPE_AGENT);
}
__device__ __forceinline__ short ld_sc16(const short* pp) {
  return __hip_atomic_load((short*)pp, __ATOMIC_RELAXED, __HIP_MEMORY_SCOPE_AGENT);
}
__device__ __forceinline__ unsigned long long ld_sc64(const void* pp) {
  return __hip_atomic_load((unsigned long long*)pp, __ATOMIC_RELAXED, __HIP_MEMORY_SCOPE_AGENT);
}
__device__ __forceinline__ bf16x8 ldfrag_sc(const short* pp) {
  union { unsigned long long q[2]; bf16x8 v; } u;
  u.q[0] = ld_sc64(pp);
  u.q[1] = ld_sc64(pp + 4);
  return u.v;
}
__device__ __forceinline__ int ldflag(int* pp) {
  return __hip_atomic_load(pp, __ATOMIC_RELAXED, __HIP_MEMORY_SCOPE_AGENT);
}
__device__ __forceinline__ void stflag(int* pp, int v) {
  __hip_atomic_store(pp, v, __ATOMIC_RELAXED, __HIP_MEMORY_SCOPE_AGENT);
}
__device__ __forceinline__ void waitf(int* f, int n, int target) {
  if (threadIdx.x < 64) {
    const int ln = threadIdx.x;
    while (1) {
      int v = (ln < n) ? ldflag(f + ln) : target;
      if (__all(v >= target)) break;
      __builtin_amdgcn_s_sleep(1);
    }
  }
  __syncthreads();
}
// publish: sc1 data stores drained (vmcnt(0)), then flag store.
__device__ __forceinline__ void pubf(int* f, int val) {
  relfence();
  __syncthreads();
  if (threadIdx.x == 0) stflag(f, val);
}

// pack W (K x N, row-major fp32) into MFMA-B fragment order:
// dst[((nt*KT+kt)*64+lane)*8+j] = W[kt*32+(lane>>4)*8+j][nt*16+(lane&15)]
__device__ __forceinline__ void pack_w(short* dst, const float* src, int KT, int N, int idx) {
  int tile = idx >> 9, rem = idx & 511;
  int lane = rem >> 3, j = rem & 7;
  int nt = tile / KT, kt = tile - nt * KT;
  int k = kt * 32 + ((lane >> 4) << 3) + j, n = (nt << 4) + (lane & 15);
  dst[idx] = f2bf(src[(int64_t)k * N + n]);
}

__global__ void __launch_bounds__(256) k_prep(P p) {
  char* ws = p.ws;
  const int64_t total = 1608032;
  for (int64_t i = (int64_t)blockIdx.x * 256 + threadIdx.x; i < total;
       i += (int64_t)gridDim.x * 256) {
    int64_t r = i;
    if (r < 262144) { pack_w((short*)(ws + OFF_WIH), p.Wih, 16, 512, (int)r); continue; }
    r -= 262144;
    if (r < 262144) { pack_w((short*)(ws + OFF_WHH), p.Whh, 16, 512, (int)r); continue; }
    r -= 262144;
    if (r < 65536) { pack_w((short*)(ws + OFF_WXH), p.Wxh, 4, 512, (int)r); continue; }
    r -= 65536;
    if (r < 131072) {  // Wicat: [mu0-63|lv0-63|mu64-127|lv64-127], KT=16
      int idx = (int)r;
      int tile = idx >> 9, rem = idx & 511, lane = rem >> 3, jj = rem & 7;
      int nt = tile >> 4, kt = tile & 15;
      int k = kt * 32 + ((lane >> 4) << 3) + jj, ccol = (nt << 4) + (lane & 15);
      int pair = ccol >> 7, within = ccol & 127, sub = within >> 6;
      int col = (within & 63) + (pair << 6);
      const float* s = sub ? p.Whl : p.Whm;
      ((short*)(ws + OFF_WICAT))[idx] = f2bf(s[(int64_t)k * 128 + col]);
      continue;
    }
    r -= 131072;
    if (r < 131072) {  // W1cat = [Wg1|Wp1], KT=4, N=1024
      int idx = (int)r;
      int tile = idx >> 9, rem = idx & 511, lane = rem >> 3, jj = rem & 7;
      int nt = tile >> 2, kt = tile & 3;
      int k = kt * 32 + ((lane >> 4) << 3) + jj, ccol = (nt << 4) + (lane & 15);
      const float* s = (ccol < 512) ? p.Wg1 : p.Wp1;
      ((short*)(ws + OFF_W1CAT))[idx] = f2bf(s[(int64_t)k * 512 + (ccol & 511)]);
      continue;
    }
    r -= 131072;
    if (r < 65536) { pack_w((short*)(ws + OFF_WG2), p.Wg2, 16, 128, (int)r); continue; }
    r -= 65536;
    if (r < 65536) { pack_w((short*)(ws + OFF_WP2), p.Wp2, 16, 128, (int)r); continue; }
    r -= 65536;
    if (r < 16384) { pack_w((short*)(ws + OFF_WMU), p.Wmu, 4, 128, (int)r); continue; }
    r -= 16384;
    if (r < 16384) { pack_w((short*)(ws + OFF_WLV), p.Wlv, 4, 128, (int)r); continue; }
    r -= 16384;
    if (r < 65536) { pack_w((short*)(ws + OFF_EW1), p.eW1, 4, 512, (int)r); continue; }
    r -= 65536;
    if (r < 262144) { pack_w((short*)(ws + OFF_EW2), p.eW2, 16, 512, (int)r); continue; }
    r -= 262144;
    if (r < 262144) { pack_w((short*)(ws + OFF_EW3), p.eW3, 16, 512, (int)r); continue; }
    r -= 262144;
    if (r < 1024) { ((float*)(ws + OFF_B1CAT))[r] = (r < 512) ? p.bg1[r] : p.bp1[r - 512]; continue; }
    r -= 1024;
    if (r < 256) {
      int ccol = (int)r; int pair = ccol >> 7, within = ccol & 127, sub = within >> 6;
      int col = (within & 63) + (pair << 6);
      ((float*)(ws + OFF_BICAT))[ccol] = sub ? p.bhl[col] : p.bhm[col];
      continue;
    }
    r -= 256;
    ((int*)(ws + OFF_XPCNT))[r] = 0;  // r < 1120: all flags/counters
  }
}

// =====================================================================
// persistent scan kernel: 128 WGs. Register-resident weights; batched
// sc1 loads (one exposed L3 latency per hop); prefetch flag-independent
// data before polls; bulk d_out stores deferred until after flag publish.
// =====================================================================
__global__ void __launch_bounds__(256, 1) k_scan(P p) {
  extern __shared__ char smem[];
  char* ws = p.ws;
  const int tid = threadIdx.x;
  const int lane = tid & 63, w = tid >> 6;
  const int l16 = lane & 15, quad = lane >> 4;
  const int wg = blockIdx.x;

  short* Xb   = (short*)(ws + OFF_X);
  short* qxbf = (short*)(ws + OFF_QXBF);
  int* xp_cnt = (int*)(ws + OFF_XPCNT);

  if (wg < 64) {
    // ---------------- xproj crew ----------------
    const int s = wg & 7, t0 = wg >> 3;
    const short* wih = (const short*)(ws + OFF_WIH);
    for (int tt = 0; tt < 128; ++tt) {
      const int t = t0 + (tt << 3);
      const int tsrc = 1023 - t;
      const float* arow = p.data + ((size_t)(w * 16 + l16) * 1024 + tsrc) * 512 + quad * 8;
      f32x4 acc[4] = {};
      for (int kt = 0; kt < 16; ++kt) {
        bf16x8 af = cvt8p(arow + kt * 32);
#pragma unroll
        for (int i = 0; i < 4; ++i) {
          const int nt = s * 4 + i;
          bf16x8 bw = ldfrag(wih + ((size_t)(nt * 16 + kt) * 64 + lane) * 8);
          acc[i] = MFMA16(af, bw, acc[i]);
        }
      }
      short* xrow = Xb + (size_t)t * 32768;
#pragma unroll
      for (int i = 0; i < 4; ++i) {
        const int col = (s * 4 + i) * 16 + l16;
        const float bias = p.bih[col] + p.bhh[col];
#pragma unroll
        for (int r = 0; r < 4; ++r) {
          const int row = w * 16 + quad * 4 + r;
          st_sc16(xrow + (size_t)row * 512 + col, f2bf(acc[i][r] + bias));
        }
      }
      relfence();
      __syncthreads();
      if (tid == 0) atomicAdd(xp_cnt + t, 1);
    }
    return;
  }

  if (wg < 80) {
    // ---------------- RNN crew ----------------
    const int id = wg - 64, g = id >> 2, c = id & 3;
    int* rf = (int*)(ws + OFF_RNNF) + g * 4;
    {
      // register-resident Whh slice: nt = c*8 + w*2 + i  (32 frags = 128 VGPR)
      const short* whh = (const short*)(ws + OFF_WHH);
      bf16x8 wb[2][16];
#pragma unroll
      for (int i = 0; i < 2; ++i) {
        const int nt = c * 8 + w * 2 + i;
#pragma unroll
        for (int kt = 0; kt < 16; ++kt)
          wb[i][kt] = ldfrag(whh + ((size_t)(nt * 16 + kt) * 64 + lane) * 8);
      }
      for (int t = 0; t < 1024; ++t) {
        if (tid < 64) {
          while (1) {
            int ok = 1;
            if (tid < 4) { if (t > 0) ok = (ldflag(rf + tid) >= t); }
            else if (tid == 4) ok = (ldflag(xp_cnt + t) >= 8);
            if (__all(ok)) break;
            __builtin_amdgcn_s_sleep(1);
          }
        }
        __syncthreads();
        // batched A-frag loads (one exposed latency)
        bf16x8 af[16];
        if (t == 0) {
#pragma unroll
          for (int kt = 0; kt < 16; ++kt) af[kt] = cvt8p(p.h0 + quad * 8 + kt * 32);
        } else {
          const short* hrow = Xb + (size_t)(t - 1) * 32768 + (size_t)(g * 16 + l16) * 512 + quad * 8;
#pragma unroll
          for (int kt = 0; kt < 16; ++kt) af[kt] = ldfrag_sc(hrow + kt * 32);
        }
        f32x4 acc[2] = {};
#pragma unroll
        for (int kt = 0; kt < 16; ++kt)
#pragma unroll
          for (int i = 0; i < 2; ++i) acc[i] = MFMA16(af[kt], wb[i][kt], acc[i]);
        short* xrow = Xb + (size_t)t * 32768;
        short xv[2][4];
#pragma unroll
        for (int i = 0; i < 2; ++i) {
          const int col = c * 128 + (w * 2 + i) * 16 + l16;
#pragma unroll
          for (int r = 0; r < 4; ++r)
            xv[i][r] = ld_sc16(xrow + (size_t)(g * 16 + quad * 4 + r) * 512 + col);
        }
#pragma unroll
        for (int i = 0; i < 2; ++i) {
          const int col = c * 128 + (w * 2 + i) * 16 + l16;
#pragma unroll
          for (int r = 0; r < 4; ++r) {
            const size_t o = (size_t)(g * 16 + quad * 4 + r) * 512 + col;
            float h = acc[i][r] + bf2f(xv[i][r]);
            st_sc16(xrow + o, f2bf(h > 0.f ? h : 0.f));
          }
        }
        pubf(rf + c, t + 1);
      }
    }
    // ---------------- re-role: inf crew ----------------
    waitf(rf, 4, 1024);  // whole group's hs complete
    const int g2 = g, r2 = c;
    short* hcb = (short*)(ws + OFF_HC);
    short* xqb = (short*)(ws + OFF_XQ);
    int* fa = (int*)(ws + OFF_INFAF) + g2 * 2;
    int* fb = (int*)(ws + OFF_INFBF) + g2 * 2;
    if (r2 < 2) {
      // stage A: h_c = 0.5*(tanh(x_prev@Wxh+bxh) + rnn_out[t]); 256-col slice
      const short* wxh = (const short*)(ws + OFF_WXH);
      bf16x8 wa[4][4];
      float bx[4];
#pragma unroll
      for (int i = 0; i < 4; ++i) {
        const int nt = r2 * 16 + w * 4 + i;
#pragma unroll
        for (int kt = 0; kt < 4; ++kt)
          wa[i][kt] = ldfrag(wxh + ((size_t)(nt * 4 + kt) * 64 + lane) * 8);
        bx[i] = p.bxh[nt * 16 + l16];
      }
      for (int t = 0; t < 1024; ++t) {
        // prefetch rnn_out (RNN phase complete -> flag-independent)
        const short* rsrc = Xb + (size_t)(1023 - t) * 32768;
        short rv[4][4];
#pragma unroll
        for (int i = 0; i < 4; ++i) {
          const int ng = r2 * 256 + (w * 4 + i) * 16 + l16;
#pragma unroll
          for (int r = 0; r < 4; ++r)
            rv[i][r] = ld_sc16(rsrc + (size_t)(g2 * 16 + quad * 4 + r) * 512 + ng);
        }
        if (t > 0) waitf(fb, 2, t);
        bf16x8 af[4];
        if (t == 0) {
#pragma unroll
          for (int kt = 0; kt < 4; ++kt) af[kt] = cvt8p(p.xq0 + quad * 8 + kt * 32);
        } else {
          const short* xrow = xqb + (size_t)(g2 * 16 + l16) * 128 + quad * 8;
#pragma unroll
          for (int kt = 0; kt < 4; ++kt) af[kt] = ldfrag_sc(xrow + kt * 32);
        }
        f32x4 acc[4] = {};
#pragma unroll
        for (int kt = 0; kt < 4; ++kt)
#pragma unroll
          for (int i = 0; i < 4; ++i) acc[i] = MFMA16(af[kt], wa[i][kt], acc[i]);
#pragma unroll
        for (int i = 0; i < 4; ++i) {
          const int ng = r2 * 256 + (w * 4 + i) * 16 + l16;
#pragma unroll
          for (int r = 0; r < 4; ++r) {
            const int row = g2 * 16 + quad * 4 + r;
            const float u = acc[i][r] + bx[i];
            const float e = __expf(2.f * u);
            const float th = 1.f - 2.f / (e + 1.f);
            const float hc = 0.5f * (th + bf2f(rv[i][r]));
            st_sc16(hcb + (size_t)row * 512 + ng, f2bf(hc));
          }
        }
        pubf(fa + r2, t + 1);
      }
    } else {
      // stage B: [mu|lv] slice from h_c; sample x_t; publish early, store late
      const int j = r2 - 2;
      const short* wicat = (const short*)(ws + OFF_WICAT);
      const float* bicat = (const float*)(ws + OFF_BICAT);
      float* scr = (float*)smem;  // [2][16][64] fp32
      bf16x8 wbv[2][16];
      float bias[2];
#pragma unroll
      for (int i = 0; i < 2; ++i) {
        const int nt = j * 8 + w * 2 + i;
#pragma unroll
        for (int kt = 0; kt < 16; ++kt)
          wbv[i][kt] = ldfrag(wicat + ((size_t)(nt * 16 + kt) * 64 + lane) * 8);
        bias[i] = bicat[nt * 16 + l16];
      }
      for (int t = 0; t < 1024; ++t) {
        // prefetch eps_q (input, flag-independent)
        float ev[4];
#pragma unroll
        for (int q2 = 0; q2 < 4; ++q2) {
          const int i2 = tid + q2 * 256;
          const int row = i2 >> 6, cl = i2 & 63;
          const int col = j * 64 + cl, b = g2 * 16 + row;
          ev[q2] = p.eps_q[((size_t)t * 64 + b) * 128 + col];
        }
        waitf(fa, 2, t + 1);
        bf16x8 af[16];
        const short* hrow2 = hcb + (size_t)(g2 * 16 + l16) * 512 + quad * 8;
#pragma unroll
        for (int kt = 0; kt < 16; ++kt) af[kt] = ldfrag_sc(hrow2 + kt * 32);
        f32x4 acc[2] = {};
#pragma unroll
        for (int kt = 0; kt < 16; ++kt)
#pragma unroll
          for (int i = 0; i < 2; ++i) acc[i] = MFMA16(af[kt], wbv[i][kt], acc[i]);
#pragma unroll
        for (int i = 0; i < 2; ++i) {
          const int catcol = (j * 8 + w * 2 + i) * 16 + l16;
          const int within = catcol & 127, sub = within >> 6;
          const int col = (within & 63) + ((catcol >> 7) << 6);
#pragma unroll
          for (int r = 0; r < 4; ++r) {
            const int row = quad * 4 + r;
            scr[(sub * 16 + row) * 64 + (col & 63)] = acc[i][r] + bias[i];
          }
        }
        __syncthreads();
        float xs[4];
#pragma unroll
        for (int q2 = 0; q2 < 4; ++q2) {
          const int i2 = tid + q2 * 256;
          const int row = i2 >> 6, cl = i2 & 63;
          const int col = j * 64 + cl, b = g2 * 16 + row;
          const float m = scr[row * 64 + cl], l = scr[1024 + row * 64 + cl];
          const float xvv = m + ev[q2] * __expf(0.5f * l);
          xs[q2] = xvv;
          st_sc16(xqb + (size_t)b * 128 + col, f2bf(xvv));
        }
        pubf(fb + j, t + 1);
        // deferred bulk outputs (off the critical chain)
#pragma unroll
        for (int i = 0; i < 2; ++i) {
          const int catcol = (j * 8 + w * 2 + i) * 16 + l16;
          const int within = catcol & 127, sub = within >> 6;
          const int col = (within & 63) + ((catcol >> 7) << 6);
          float* dbase = p.out + (sub ? QLV_O : QMU_O);
#pragma unroll
          for (int r = 0; r < 4; ++r) {
            const int row = quad * 4 + r, b = g2 * 16 + row;
            dbase[(size_t)b * 131072 + (size_t)t * 128 + col] = acc[i][r] + bias[i];
          }
        }
#pragma unroll
        for (int q2 = 0; q2 < 4; ++q2) {
          const int i2 = tid + q2 * 256;
          const int row = i2 >> 6, cl = i2 & 63;
          const int col = j * 64 + cl, b = g2 * 16 + row;
          p.out[QX_O + (size_t)b * 131072 + (size_t)t * 128 + col] = xs[q2];
          qxbf[((size_t)b * 1024 + t) * 128 + col] = f2bf(xs[q2]);
        }
      }
    }
    return;
  }

  // ---------------- gen crew ----------------
  {
    const int id = wg - 80, g3 = id / 12, r3 = id % 12;
    short* u1b = (short*)(ws + OFF_U1);
    short* pmb = (short*)(ws + OFF_PM);
    short* mub = (short*)(ws + OFF_MU);
    short* xgb = (short*)(ws + OFF_XG);
    int* fga = (int*)(ws + OFF_GENAF) + g3 * 4;
    int* fgb = (int*)(ws + OFF_GENBF) + g3 * 8;
    if (r3 < 4) {
      // stage A: lv_{t-1}(full, redundant) -> x_{t-1} -> u1_t slice
      short* xl = (short*)smem;  // [16][128] bf16, local x_{t-1}
      const float* b1cat = (const float*)(ws + OFF_B1CAT);
      const short* w1cat = (const short*)(ws + OFF_W1CAT);
      const short* wlvp = (const short*)(ws + OFF_WLV);
      bf16x8 wg1[4][4]; float b1[4];
#pragma unroll
      for (int i = 0; i < 4; ++i) {
        const int nt = r3 * 16 + w * 4 + i;
#pragma unroll
        for (int kt = 0; kt < 4; ++kt)
          wg1[i][kt] = ldfrag(w1cat + ((size_t)(nt * 4 + kt) * 64 + lane) * 8);
        b1[i] = b1cat[nt * 16 + l16];
      }
      bf16x8 wlv[2][4]; float bl[2];
#pragma unroll
      for (int i = 0; i < 2; ++i) {
        const int nt = w * 2 + i;
#pragma unroll
        for (int kt = 0; kt < 4; ++kt)
          wlv[i][kt] = ldfrag(wlvp + ((size_t)(nt * 4 + kt) * 64 + lane) * 8);
        bl[i] = p.blv[nt * 16 + l16];
      }
      for (int t = 0; t <= 1024; ++t) {
        float lvs[2][4], xvs[2][4];
        const bool last = (t == 1024);
        if (t == 0) {
          for (int i2 = tid; i2 < 2048; i2 += 256) xl[i2] = f2bf(p.x0[i2 & 127]);
          __syncthreads();
        } else {
          // prefetch eps_p (input, flag-independent)
          float ep[2][4];
#pragma unroll
          for (int i = 0; i < 2; ++i) {
            const int col = (w * 2 + i) * 16 + l16;
#pragma unroll
            for (int r = 0; r < 4; ++r) {
              const int b = g3 * 16 + quad * 4 + r;
              ep[i][r] = p.eps_p[((size_t)(t - 1) * 64 + b) * 128 + col];
            }
          }
          waitf(fgb, 8, t);
          bf16x8 paf[4];
          const short* pmrow = pmb + (size_t)(g3 * 16 + l16) * 128 + quad * 8;
#pragma unroll
          for (int kt = 0; kt < 4; ++kt) paf[kt] = relu8(ldfrag_sc(pmrow + kt * 32));
          short mv[2][4];
#pragma unroll
          for (int i = 0; i < 2; ++i) {
            const int col = (w * 2 + i) * 16 + l16;
#pragma unroll
            for (int r = 0; r < 4; ++r)
              mv[i][r] = ld_sc16(mub + (size_t)(g3 * 16 + quad * 4 + r) * 128 + col);
          }
          f32x4 acl[2] = {};
#pragma unroll
          for (int kt = 0; kt < 4; ++kt)
#pragma unroll
            for (int i = 0; i < 2; ++i) acl[i] = MFMA16(paf[kt], wlv[i][kt], acl[i]);
#pragma unroll
          for (int i = 0; i < 2; ++i) {
            const int col = (w * 2 + i) * 16 + l16;
#pragma unroll
            for (int r = 0; r < 4; ++r) {
              const int row = quad * 4 + r;
              const float lv = acl[i][r] + bl[i];
              const float xv2 = bf2f(mv[i][r]) + ep[i][r] * __expf(0.5f * lv);
              lvs[i][r] = lv; xvs[i][r] = xv2;
              xl[row * 128 + col] = f2bf(xv2);
            }
          }
          __syncthreads();
        }
        if (!last) {
          bf16x8 xf[4];
          const short* xrow = xl + l16 * 128 + quad * 8;
#pragma unroll
          for (int kt = 0; kt < 4; ++kt) xf[kt] = ldfrag(xrow + kt * 32);
          f32x4 acc[4] = {};
#pragma unroll
          for (int kt = 0; kt < 4; ++kt)
#pragma unroll
            for (int i = 0; i < 4; ++i) acc[i] = MFMA16(xf[kt], wg1[i][kt], acc[i]);
#pragma unroll
          for (int i = 0; i < 4; ++i) {
            const int c1 = (r3 * 16 + w * 4 + i) * 16 + l16;
#pragma unroll
            for (int r = 0; r < 4; ++r) {
              const int row = quad * 4 + r;
              const float u = acc[i][r] + b1[i];
              st_sc16(u1b + (size_t)(g3 * 16 + row) * 1024 + c1, f2bf(u > 0.f ? u : 0.f));
            }
          }
          if (r3 == 0)
            for (int i2 = tid; i2 < 2048; i2 += 256) st_sc16(xgb + (size_t)g3 * 2048 + i2, xl[i2]);
          pubf(fga + r3, t + 1);
        }
        // deferred p_lv / p_x outputs for step t-1
        if (t > 0 && w == r3) {
#pragma unroll
          for (int i = 0; i < 2; ++i) {
            const int col = (w * 2 + i) * 16 + l16;
#pragma unroll
            for (int r = 0; r < 4; ++r) {
              const int b = g3 * 16 + quad * 4 + r;
              p.out[PLV_O + (size_t)b * 131072 + (size_t)(t - 1) * 128 + col] = lvs[i][r];
              p.out[PX_O + (size_t)b * 131072 + (size_t)(t - 1) * 128 + col] = xvs[i][r];
            }
          }
        }
        if (last) break;
      }
    } else {
      // stage B: pm full (redundant), gate split across waves 0/2, xmu on wave 1
      const int j = r3 - 4;
      short* spm = (short*)smem;            // [16][128] bf16
      float* sg0 = (float*)(smem + 4096);   // [16][16]
      float* sg1 = (float*)(smem + 5120);   // [16][16]
      float* sxm = (float*)(smem + 6144);   // [16][16]
      const short* wp2p = (const short*)(ws + OFF_WP2);
      const short* wg2p = (const short*)(ws + OFF_WG2) + (size_t)j * 8192;
      const short* wmup = (const short*)(ws + OFF_WMU) + (size_t)j * 2048;
      bf16x8 wp2[2][16]; float bp[2];
#pragma unroll
      for (int i = 0; i < 2; ++i) {
        const int nt = w * 2 + i;
#pragma unroll
        for (int kt = 0; kt < 16; ++kt)
          wp2[i][kt] = ldfrag(wp2p + ((size_t)(nt * 16 + kt) * 64 + lane) * 8);
        bp[i] = p.bp2[nt * 16 + l16];
      }
      bf16x8 wg2r[8];
      if (w == 0 || w == 2) {
        const int koff = (w == 0) ? 0 : 8;
#pragma unroll
        for (int kt = 0; kt < 8; ++kt)
          wg2r[kt] = ldfrag(wg2p + ((size_t)(koff + kt) * 64 + lane) * 8);
      }
      bf16x8 wmu[4];
      if (w == 1) {
#pragma unroll
        for (int kt = 0; kt < 4; ++kt)
          wmu[kt] = ldfrag(wmup + ((size_t)kt * 64 + lane) * 8);
      }
      const int mrow = tid >> 4, mcl = tid & 15;
      const int mcol = j * 16 + mcl, mb = g3 * 16 + mrow;
      const float bg2v = p.bg2[mcol], bmuv = p.bmu[mcol];
      for (int t = 0; t < 1024; ++t) {
        waitf(fga, 4, t + 1);
        bf16x8 uf[16];
        const short* u1p = u1b + (size_t)(g3 * 16 + l16) * 1024 + 512 + quad * 8;
#pragma unroll
        for (int kt = 0; kt < 16; ++kt) uf[kt] = ldfrag_sc(u1p + kt * 32);
        bf16x8 gf[8];
        if (w == 0 || w == 2) {
          const int koff = (w == 0) ? 0 : 8;
          const short* u1g = u1b + (size_t)(g3 * 16 + l16) * 1024 + koff * 32 + quad * 8;
#pragma unroll
          for (int kt = 0; kt < 8; ++kt) gf[kt] = ldfrag_sc(u1g + kt * 32);
        }
        bf16x8 xf2[4];
        if (w == 1) {
          const short* xg = xgb + (size_t)(g3 * 16 + l16) * 128 + quad * 8;
#pragma unroll
          for (int kt = 0; kt < 4; ++kt) xf2[kt] = ldfrag_sc(xg + kt * 32);
        }
        f32x4 acc[2] = {};
#pragma unroll
        for (int kt = 0; kt < 16; ++kt)
#pragma unroll
          for (int i = 0; i < 2; ++i) acc[i] = MFMA16(uf[kt], wp2[i][kt], acc[i]);
#pragma unroll
        for (int i = 0; i < 2; ++i) {
          const int col = (w * 2 + i) * 16 + l16;
#pragma unroll
          for (int r = 0; r < 4; ++r) spm[(quad * 4 + r) * 128 + col] = f2bf(acc[i][r] + bp[i]);
        }
        if (w == 0 || w == 2) {
          f32x4 ga = {};
#pragma unroll
          for (int kt = 0; kt < 8; ++kt) ga = MFMA16(gf[kt], wg2r[kt], ga);
          float* sgd = (w == 0) ? sg0 : sg1;
#pragma unroll
          for (int r = 0; r < 4; ++r) sgd[(quad * 4 + r) * 16 + l16] = ga[r];
        } else if (w == 1) {
          f32x4 xm = {};
#pragma unroll
          for (int kt = 0; kt < 4; ++kt) xm = MFMA16(xf2[kt], wmu[kt], xm);
#pragma unroll
          for (int r = 0; r < 4; ++r) sxm[(quad * 4 + r) * 16 + l16] = xm[r];
        }
        __syncthreads();
        float muv;
        {
          const float gv = 1.f / (1.f + __expf(-(sg0[mrow * 16 + mcl] + sg1[mrow * 16 + mcl] + bg2v)));
          const float xmv = sxm[mrow * 16 + mcl] + bmuv;
          const float pmv = bf2f(spm[mrow * 128 + mcol]);
          muv = (1.f - gv) * xmv + gv * pmv;
          st_sc16(mub + (size_t)mb * 128 + mcol, f2bf(muv));
        }
        if (j == 0)
          for (int i2 = tid; i2 < 2048; i2 += 256) st_sc16(pmb + (size_t)g3 * 2048 + i2, spm[i2]);
        pubf(fgb + j, t + 1);
        p.out[PMU_O + (size_t)mb * 131072 + (size_t)t * 128 + mcol] = muv;  // deferred
      }
    }
    return;
  }
}

// =====================================================================
// fused emission MLP: y = sigmoid(relu(relu(qx@W1+b1)@W2+b2)@W3+b3)
// =====================================================================
__global__ void __launch_bounds__(256) k_emis(P p) {
  extern __shared__ char smem[];
  short* h1 = (short*)smem;            // [64][520] bf16 (pad 8 -> 2-way banks)
  short* h2 = (short*)(smem + 66560);  // [64][520]
  const int tid = threadIdx.x, lane = tid & 63, w = tid >> 6;
  const int l16 = lane & 15, quad = lane >> 4;
  const size_t m0 = (size_t)blockIdx.x * 64;
  const short* qx  = (const short*)(p.ws + OFF_QXBF);
  const short* ew1 = (const short*)(p.ws + OFF_EW1);
  const short* ew2 = (const short*)(p.ws + OFF_EW2);
  const short* ew3 = (const short*)(p.ws + OFF_EW3);
  for (int nc = 0; nc < 2; ++nc) {
    f32x4 acc[4][4] = {};
    for (int kt = 0; kt < 4; ++kt) {
      bf16x8 bw[4];
#pragma unroll
      for (int i = 0; i < 4; ++i) {
        const int nt = w * 8 + nc * 4 + i;
        bw[i] = ldfrag(ew1 + ((size_t)(nt * 4 + kt) * 64 + lane) * 8);
      }
#pragma unroll
      for (int mt = 0; mt < 4; ++mt) {
        bf16x8 af = ldfrag(qx + (m0 + mt * 16 + l16) * 128 + kt * 32 + quad * 8);
#pragma unroll
        for (int i = 0; i < 4; ++i) acc[mt][i] = MFMA16(af, bw[i], acc[mt][i]);
      }
    }
#pragma unroll
    for (int mt = 0; mt < 4; ++mt)
#pragma unroll
      for (int i = 0; i < 4; ++i) {
        const int col = (w * 8 + nc * 4 + i) * 16 + l16;
        const float bias = p.eb1[col];
#pragma unroll
        for (int r = 0; r < 4; ++r) {
          const float v = acc[mt][i][r] + bias;
          h1[(mt * 16 + quad * 4 + r) * 520 + col] = f2bf(v > 0.f ? v : 0.f);
        }
      }
  }
  __syncthreads();
  for (int nc = 0; nc < 2; ++nc) {
    f32x4 acc[4][4] = {};
    for (int kt = 0; kt < 16; ++kt) {
      bf16x8 bw[4];
#pragma unroll
      for (int i = 0; i < 4; ++i) {
        const int nt = w * 8 + nc * 4 + i;
        bw[i] = ldfrag(ew2 + ((size_t)(nt * 16 + kt) * 64 + lane) * 8);
      }
#pragma unroll
      for (int mt = 0; mt < 4; ++mt) {
        bf16x8 af = ldfrag(h1 + (mt * 16 + l16) * 520 + kt * 32 + quad * 8);
#pragma unroll
        for (int i = 0; i < 4; ++i) acc[mt][i] = MFMA16(af, bw[i], acc[mt][i]);
      }
    }
#pragma unroll
    for (int mt = 0; mt < 4; ++mt)
#pragma unroll
      for (int i = 0; i < 4; ++i) {
        const int col = (w * 8 + nc * 4 + i) * 16 + l16;
        const float bias = p.eb2[col];
#pragma unroll
        for (int r = 0; r < 4; ++r) {
          const float v = acc[mt][i][r] + bias;
          h2[(mt * 16 + quad * 4 + r) * 520 + col] = f2bf(v > 0.f ? v : 0.f);
        }
      }
  }
  __syncthreads();
  for (int nc = 0; nc < 2; ++nc) {
    f32x4 acc[4][4] = {};
    for (int kt = 0; kt < 16; ++kt) {
      bf16x8 bw[4];
#pragma unroll
      for (int i = 0; i < 4; ++i) {
        const int nt = w * 8 + nc * 4 + i;
        bw[i] = ldfrag(ew3 + ((size_t)(nt * 16 + kt) * 64 + lane) * 8);
      }
#pragma unroll
      for (int mt = 0; mt < 4; ++mt) {
        bf16x8 af = ldfrag(h2 + (mt * 16 + l16) * 520 + kt * 32 + quad * 8);
#pragma unroll
        for (int i = 0; i < 4; ++i) acc[mt][i] = MFMA16(af, bw[i], acc[mt][i]);
      }
    }
#pragma unroll
    for (int mt = 0; mt < 4; ++mt)
#pragma unroll
      for (int i = 0; i < 4; ++i) {
        const int col = (w * 8 + nc * 4 + i) * 16 + l16;
        const float bias = p.eb3[col];
#pragma unroll
        for (int r = 0; r < 4; ++r) {
          const size_t m = m0 + mt * 16 + quad * 4 + r;
          const size_t b = m >> 10, tt2 = m & 1023;
          const float v = acc[mt][i][r] + bias;
          p.out[Y_O + (b << 19) + tt2 * 512 + col] = 1.f / (1.f + __expf(-v));
        }
      }
  }
}

extern "C" void kernel_launch(void* const* d_in, const int* in_sizes, int n_in,
                              void* d_out, int out_size, void* d_ws, size_t ws_size,
                              hipStream_t stream) {
  (void)in_sizes; (void)n_in; (void)out_size; (void)ws_size;
  P p;
  p.ws = (char*)d_ws; p.out = (float*)d_out;
  p.data = (const float*)d_in[0];
  p.eps_q = (const float*)d_in[1];
  p.eps_p = (const float*)d_in[2];
  p.Wih = (const float*)d_in[3]; p.Whh = (const float*)d_in[4];
  p.bih = (const float*)d_in[5]; p.bhh = (const float*)d_in[6];
  p.h0 = (const float*)d_in[7]; p.xq0 = (const float*)d_in[8]; p.x0 = (const float*)d_in[9];
  p.Wxh = (const float*)d_in[10]; p.bxh = (const float*)d_in[11];
  p.Whm = (const float*)d_in[12]; p.bhm = (const float*)d_in[13];
  p.Whl = (const float*)d_in[14]; p.bhl = (const float*)d_in[15];
  p.Wg1 = (const float*)d_in[16]; p.bg1 = (const float*)d_in[17];
  p.Wg2 = (const float*)d_in[18]; p.bg2 = (const float*)d_in[19];
  p.Wp1 = (const float*)d_in[20]; p.bp1 = (const float*)d_in[21];
  p.Wp2 = (const float*)d_in[22]; p.bp2 = (const float*)d_in[23];
  p.Wmu = (const float*)d_in[24]; p.bmu = (const float*)d_in[25];
  p.Wlv = (const float*)d_in[26]; p.blv = (const float*)d_in[27];
  p.eW1 = (const float*)d_in[28]; p.eb1 = (const float*)d_in[29];
  p.eW2 = (const float*)d_in[30]; p.eb2 = (const float*)d_in[31];
  p.eW3 = (const float*)d_in[32]; p.eb3 = (const float*)d_in[33];

  hipFuncSetAttribute(reinterpret_cast<const void*>(k_scan),
                      hipFuncAttributeMaxDynamicSharedMemorySize, SMEM_SCAN);
  hipFuncSetAttribute(reinterpret_cast<const void*>(k_emis),
                      hipFuncAttributeMaxDynamicSharedMemorySize, SMEM_EMIS);

  k_prep<<<dim3(2048), dim3(256), 0, stream>>>(p);
  k_scan<<<dim3(128), dim3(256), SMEM_SCAN, stream>>>(p);
  k_emis<<<dim3(1024), dim3(256), SMEM_EMIS, stream>>>(p);
}

// Round 3
// 13883.418 us; speedup vs baseline: 2.3928x; 1.0975x over previous
//
#include <hip/hip_runtime.h>
#include <stdint.h>

typedef __bf16 bf16x8 __attribute__((ext_vector_type(8)));
typedef short  s16x8  __attribute__((ext_vector_type(8)));
typedef float  f32x4  __attribute__((ext_vector_type(4)));

#define MFMA16(a, b, c) __builtin_amdgcn_mfma_f32_16x16x32_bf16((a), (b), (c), 0, 0, 0)

// ---------------- workspace layout (bytes) ----------------
#define OFF_X      0ull          // (T,64,512) bf16: xp, h written over own cols
#define OFF_QXBF   67108864ull   // (B,T,128) bf16 copy of q_x for emission
#define OFF_WIH    83886080ull
#define OFF_WHH    84410368ull
#define OFF_WXH    84934656ull
#define OFF_WICAT  85065728ull   // [Whm|Whl] interleaved 64-col blocks, N=256
#define OFF_W1CAT  85327872ull   // [Wg1|Wp1], N=1024
#define OFF_WG2    85590016ull
#define OFF_WP2    85721088ull
#define OFF_WMU    85852160ull
#define OFF_WLV    85884928ull
#define OFF_EW1    85917696ull
#define OFF_EW2    86048768ull
#define OFF_EW3    86573056ull
#define OFF_B1CAT  87097344ull   // fp32 [1024]
#define OFF_BICAT  87101440ull   // fp32 [256]
#define OFF_HX     87102464ull   // RNN cross-half ring [4g][2 slot][2 half][16][256] bf16 = 128KB
#define OFF_XPCNT  87364608ull   // int[1024]
#define OFF_RNNF   87368704ull   // int[16]

// ---------------- d_out offsets (floats) ----------------
#define QX_O  0ull
#define QMU_O 8388608ull
#define QLV_O 16777216ull
#define PX_O  25165824ull
#define PMU_O 33554432ull
#define PLV_O 41943040ull
#define Y_O   50331648ull

#define SMEM_SCAN 159744
#define SMEM_EMIS 133120

struct P {
  char* ws; float* out;
  const float *data, *eps_q, *eps_p;
  const float *Wih, *Whh, *bih, *bhh, *h0, *xq0, *x0;
  const float *Wxh, *bxh, *Whm, *bhm, *Whl, *bhl;
  const float *Wg1, *bg1, *Wg2, *bg2, *Wp1, *bp1, *Wp2, *bp2, *Wmu, *bmu, *Wlv, *blv;
  const float *eW1, *eb1, *eW2, *eb2, *eW3, *eb3;
};

__device__ __forceinline__ short f2bf(float f) {
  union { float f; uint32_t u; } v; v.f = f;
  uint32_t r = (v.u + 0x7FFFu + ((v.u >> 16) & 1u)) >> 16;
  return (short)(uint16_t)r;
}
__device__ __forceinline__ float bf2f(short s) {
  union { uint32_t u; float f; } v; v.u = ((uint32_t)(uint16_t)s) << 16;
  return v.f;
}
__device__ __forceinline__ bf16x8 ldfrag(const short* pp) { return *(const bf16x8*)pp; }
__device__ __forceinline__ bf16x8 cvt8p(const float* pp) {
  bf16x8 r;
#pragma unroll
  for (int i = 0; i < 8; ++i) r[i] = (__bf16)pp[i];
  return r;
}
__device__ __forceinline__ bf16x8 relu8(bf16x8 a) {
  s16x8 s = __builtin_bit_cast(s16x8, a);
#pragma unroll
  for (int i = 0; i < 8; ++i) s[i] = (s[i] < 0) ? (short)0 : s[i];
  return __builtin_bit_cast(bf16x8, s);
}

// -------- agent-scope (sc1, L2-bypass) communication primitives --------
__device__ __forceinline__ void relfence() {
  asm volatile("s_waitcnt vmcnt(0)" ::: "memory");
}
__device__ __forceinline__ void st_sc16(short* pp, short v) {
  __hip_atomic_store(pp, v, __ATOMIC_RELAXED, __HIP_MEMORY_SCOPE_AGENT);
}
__device__ __forceinline__ short ld_sc16(const short* pp) {
  return __hip_atomic_load((short*)pp, __ATOMIC_RELAXED, __HIP_MEMORY_SCOPE_AGENT);
}
__device__ __forceinline__ unsigned long long ld_sc64(const void* pp) {
  return __hip_atomic_load((unsigned long long*)pp, __ATOMIC_RELAXED, __HIP_MEMORY_SCOPE_AGENT);
}
__device__ __forceinline__ bf16x8 ldfrag_sc(const short* pp) {
  union { unsigned long long q[2]; bf16x8 v; } u;
  u.q[0] = ld_sc64(pp);
  u.q[1] = ld_sc64(pp + 4);
  return u.v;
}
__device__ __forceinline__ int ldflag(int* pp) {
  return __hip_atomic_load(pp, __ATOMIC_RELAXED, __HIP_MEMORY_SCOPE_AGENT);
}
__device__ __forceinline__ void stflag(int* pp, int v) {
  __hip_atomic_store(pp, v, __ATOMIC_RELAXED, __HIP_MEMORY_SCOPE_AGENT);
}
__device__ __forceinline__ void waitf(int* f, int n, int target) {
  if (threadIdx.x < 64) {
    const int ln = threadIdx.x;
    while (1) {
      int v = (ln < n) ? ldflag(f + ln) : target;
      if (__all(v >= target)) break;
      __builtin_amdgcn_s_sleep(1);
    }
  }
  __syncthreads();
}
__device__ __forceinline__ void pubf(int* f, int val) {
  relfence();
  __syncthreads();
  if (threadIdx.x == 0) stflag(f, val);
}
__device__ __forceinline__ void cpy16(void* dst, const void* src, int n16) {
  float4* d = (float4*)dst; const float4* s = (const float4*)src;
  for (int i = threadIdx.x; i < n16; i += 256) d[i] = s[i];
}

// pack W (K x N, row-major fp32) into MFMA-B fragment order:
// dst[((nt*KT+kt)*64+lane)*8+j] = W[kt*32+(lane>>4)*8+j][nt*16+(lane&15)]
__device__ __forceinline__ void pack_w(short* dst, const float* src, int KT, int N, int idx) {
  int tile = idx >> 9, rem = idx & 511;
  int lane = rem >> 3, j = rem & 7;
  int nt = tile / KT, kt = tile - nt * KT;
  int k = kt * 32 + ((lane >> 4) << 3) + j, n = (nt << 4) + (lane & 15);
  dst[idx] = f2bf(src[(int64_t)k * N + n]);
}

__global__ void __launch_bounds__(256) k_prep(P p) {
  char* ws = p.ws;
  const int64_t total = 1608032;
  for (int64_t i = (int64_t)blockIdx.x * 256 + threadIdx.x; i < total;
       i += (int64_t)gridDim.x * 256) {
    int64_t r = i;
    if (r < 262144) { pack_w((short*)(ws + OFF_WIH), p.Wih, 16, 512, (int)r); continue; }
    r -= 262144;
    if (r < 262144) { pack_w((short*)(ws + OFF_WHH), p.Whh, 16, 512, (int)r); continue; }
    r -= 262144;
    if (r < 65536) { pack_w((short*)(ws + OFF_WXH), p.Wxh, 4, 512, (int)r); continue; }
    r -= 65536;
    if (r < 131072) {  // Wicat
      int idx = (int)r;
      int tile = idx >> 9, rem = idx & 511, lane = rem >> 3, jj = rem & 7;
      int nt = tile >> 4, kt = tile & 15;
      int k = kt * 32 + ((lane >> 4) << 3) + jj, ccol = (nt << 4) + (lane & 15);
      int pair = ccol >> 7, within = ccol & 127, sub = within >> 6;
      int col = (within & 63) + (pair << 6);
      const float* s = sub ? p.Whl : p.Whm;
      ((short*)(ws + OFF_WICAT))[idx] = f2bf(s[(int64_t)k * 128 + col]);
      continue;
    }
    r -= 131072;
    if (r < 131072) {  // W1cat = [Wg1|Wp1]
      int idx = (int)r;
      int tile = idx >> 9, rem = idx & 511, lane = rem >> 3, jj = rem & 7;
      int nt = tile >> 2, kt = tile & 3;
      int k = kt * 32 + ((lane >> 4) << 3) + jj, ccol = (nt << 4) + (lane & 15);
      const float* s = (ccol < 512) ? p.Wg1 : p.Wp1;
      ((short*)(ws + OFF_W1CAT))[idx] = f2bf(s[(int64_t)k * 512 + (ccol & 511)]);
      continue;
    }
    r -= 131072;
    if (r < 65536) { pack_w((short*)(ws + OFF_WG2), p.Wg2, 16, 128, (int)r); continue; }
    r -= 65536;
    if (r < 65536) { pack_w((short*)(ws + OFF_WP2), p.Wp2, 16, 128, (int)r); continue; }
    r -= 65536;
    if (r < 16384) { pack_w((short*)(ws + OFF_WMU), p.Wmu, 4, 128, (int)r); continue; }
    r -= 16384;
    if (r < 16384) { pack_w((short*)(ws + OFF_WLV), p.Wlv, 4, 128, (int)r); continue; }
    r -= 16384;
    if (r < 65536) { pack_w((short*)(ws + OFF_EW1), p.eW1, 4, 512, (int)r); continue; }
    r -= 65536;
    if (r < 262144) { pack_w((short*)(ws + OFF_EW2), p.eW2, 16, 512, (int)r); continue; }
    r -= 262144;
    if (r < 262144) { pack_w((short*)(ws + OFF_EW3), p.eW3, 16, 512, (int)r); continue; }
    r -= 262144;
    if (r < 1024) { ((float*)(ws + OFF_B1CAT))[r] = (r < 512) ? p.bg1[r] : p.bp1[r - 512]; continue; }
    r -= 1024;
    if (r < 256) {
      int ccol = (int)r; int pair = ccol >> 7, within = ccol & 127, sub = within >> 6;
      int col = (within & 63) + (pair << 6);
      ((float*)(ws + OFF_BICAT))[ccol] = sub ? p.bhl[col] : p.bhm[col];
      continue;
    }
    r -= 256;
    ((int*)(ws + OFF_XPCNT))[r] = 0;  // r < 1120: flags/counters
  }
}

// =====================================================================
// persistent scan kernel: 76 WGs.
//   [0,64):  xproj crew (unchanged)
//   [64,72): RNN crew: 4 groups x 2 col-halves, 1 hop/step fan-in 1;
//            the k==0 WG re-roles to a ZERO-HOP single-WG inf crew
//   [72,76): gen crew: 1 WG per group, ZERO hops (all intra-WG)
// =====================================================================
__global__ void __launch_bounds__(256, 1) k_scan(P p) {
  extern __shared__ char smem[];
  char* ws = p.ws;
  const int tid = threadIdx.x;
  const int lane = tid & 63, w = tid >> 6;
  const int l16 = lane & 15, quad = lane >> 4;
  const int wg = blockIdx.x;

  short* Xb   = (short*)(ws + OFF_X);
  short* qxbf = (short*)(ws + OFF_QXBF);
  int* xp_cnt = (int*)(ws + OFF_XPCNT);

  if (wg < 64) {
    // ---------------- xproj crew ----------------
    const int s = wg & 7, t0 = wg >> 3;
    const short* wih = (const short*)(ws + OFF_WIH);
    for (int tt = 0; tt < 128; ++tt) {
      const int t = t0 + (tt << 3);
      const int tsrc = 1023 - t;
      const float* arow = p.data + ((size_t)(w * 16 + l16) * 1024 + tsrc) * 512 + quad * 8;
      f32x4 acc[4] = {};
      for (int kt = 0; kt < 16; ++kt) {
        bf16x8 af = cvt8p(arow + kt * 32);
#pragma unroll
        for (int i = 0; i < 4; ++i) {
          const int nt = s * 4 + i;
          bf16x8 bw = ldfrag(wih + ((size_t)(nt * 16 + kt) * 64 + lane) * 8);
          acc[i] = MFMA16(af, bw, acc[i]);
        }
      }
      short* xrow = Xb + (size_t)t * 32768;
#pragma unroll
      for (int i = 0; i < 4; ++i) {
        const int col = (s * 4 + i) * 16 + l16;
        const float bias = p.bih[col] + p.bhh[col];
#pragma unroll
        for (int r = 0; r < 4; ++r) {
          const int row = w * 16 + quad * 4 + r;
          st_sc16(xrow + (size_t)row * 512 + col, f2bf(acc[i][r] + bias));
        }
      }
      relfence();
      __syncthreads();
      if (tid == 0) atomicAdd(xp_cnt + t, 1);
    }
    return;
  }

  if (wg < 72) {
    // ---------------- RNN crew: group g, half k (256 cols each) -------
    const int id = wg - 64, g = id >> 1, k = id & 1;
    int* rf = (int*)(ws + OFF_RNNF) + g * 4;
    short* hxb = (short*)(ws + OFF_HX);   // [(g*2+slot)*2+half][16][256]
    short* hl = (short*)smem;             // [16][256] own half of h(t-1)
    {
      const short* whh = (const short*)(ws + OFF_WHH);
      bf16x8 wb[4][16];
#pragma unroll
      for (int i = 0; i < 4; ++i) {
        const int nt = k * 16 + w * 4 + i;
#pragma unroll
        for (int kt = 0; kt < 16; ++kt)
          wb[i][kt] = ldfrag(whh + ((size_t)(nt * 16 + kt) * 64 + lane) * 8);
      }
      for (int t = 0; t < 1024; ++t) {
        if (tid < 64) {
          while (1) {
            int ok = 1;
            if (tid == 0) { if (t > 0) ok = (ldflag(rf + (1 - k)) >= t); }
            else if (tid == 1) ok = (ldflag(xp_cnt + t) >= 8);
            if (__all(ok)) break;
            __builtin_amdgcn_s_sleep(1);
          }
        }
        __syncthreads();
        bf16x8 af[16];
        short xv[4][4];
        if (t == 0) {
#pragma unroll
          for (int kt = 0; kt < 16; ++kt) af[kt] = cvt8p(p.h0 + kt * 32 + quad * 8);
        } else {
          // other half via sc1 ring (issue first: longest latency)
          const short* hs = hxb + (((size_t)(g * 2 + ((t - 1) & 1)) * 2 + (1 - k)) * 4096);
#pragma unroll
          for (int kt = 0; kt < 8; ++kt)
            af[(1 - k) * 8 + kt] = ldfrag_sc(hs + l16 * 256 + kt * 32 + quad * 8);
        }
        // xp for own cols (sc1, issued before MFMA waits)
        {
          const short* xrow = Xb + (size_t)t * 32768;
#pragma unroll
          for (int i = 0; i < 4; ++i) {
            const int col = k * 256 + (w * 4 + i) * 16 + l16;
#pragma unroll
            for (int r = 0; r < 4; ++r)
              xv[i][r] = ld_sc16(xrow + (size_t)(g * 16 + quad * 4 + r) * 512 + col);
          }
        }
        if (t > 0) {
          // own half from LDS
#pragma unroll
          for (int kt = 0; kt < 8; ++kt)
            af[k * 8 + kt] = ldfrag(hl + l16 * 256 + kt * 32 + quad * 8);
        }
        f32x4 acc[4] = {};
#pragma unroll
        for (int kt = 0; kt < 16; ++kt)
#pragma unroll
          for (int i = 0; i < 4; ++i) acc[i] = MFMA16(af[kt], wb[i][kt], acc[i]);
        short* hdst = hxb + (((size_t)(g * 2 + (t & 1)) * 2 + k) * 4096);
        short* xrow = Xb + (size_t)t * 32768;
#pragma unroll
        for (int i = 0; i < 4; ++i) {
          const int cl = (w * 4 + i) * 16 + l16;      // local col in half
          const int col = k * 256 + cl;
#pragma unroll
          for (int r = 0; r < 4; ++r) {
            const int row = quad * 4 + r;
            float h = acc[i][r] + bf2f(xv[i][r]);
            const short hv = f2bf(h > 0.f ? h : 0.f);
            hl[row * 256 + cl] = hv;                                  // self (LDS)
            st_sc16(hdst + row * 256 + cl, hv);                       // partner
            st_sc16(xrow + (size_t)(g * 16 + row) * 512 + col, hv);   // history for inf
          }
        }
        pubf(rf + k, t + 1);
      }
    }
    if (k == 1) return;
    // ---------------- re-role: ZERO-HOP inf crew for group g ----------
    waitf(rf, 2, 1024);  // partner's final h published -> Xb complete
    const int g2 = g;
    // LDS: Wxh [0,131072) | hc [131072,147456) | xq [147456,151552) | scr f32 [151552,159744)
    short* ldsWxh = (short*)smem;
    short* hcl = (short*)(smem + 131072);
    short* xql = (short*)(smem + 147456);
    float* scr = (float*)(smem + 151552);  // [2][16][64]
    cpy16(smem, ws + OFF_WXH, 8192);
    const short* wicat = (const short*)(ws + OFF_WICAT);
    const float* bicat = (const float*)(ws + OFF_BICAT);
    bf16x8 wbv[4][16];
    float bias2[4];
#pragma unroll
    for (int i = 0; i < 4; ++i) {
      const int nt = w * 4 + i;
#pragma unroll
      for (int kt = 0; kt < 16; ++kt)
        wbv[i][kt] = ldfrag(wicat + ((size_t)(nt * 16 + kt) * 64 + lane) * 8);
      bias2[i] = bicat[nt * 16 + l16];
    }
    float bx[8];
#pragma unroll
    for (int i = 0; i < 8; ++i) bx[i] = p.bxh[(w * 8 + i) * 16 + l16];
    __syncthreads();
    for (int t = 0; t < 1024; ++t) {
      // prefetch rnn_out row (sc1) + eps_q (normal) — flag-free
      short rv[8][4];
      {
        const short* rsrc = Xb + (size_t)(1023 - t) * 32768;
#pragma unroll
        for (int i = 0; i < 8; ++i) {
          const int ng = (w * 8 + i) * 16 + l16;
#pragma unroll
          for (int r = 0; r < 4; ++r)
            rv[i][r] = ld_sc16(rsrc + (size_t)(g2 * 16 + quad * 4 + r) * 512 + ng);
        }
      }
      float ev[8];
#pragma unroll
      for (int pp = 0; pp < 2; ++pp)
#pragma unroll
        for (int q2 = 0; q2 < 4; ++q2) {
          const int idx = tid + q2 * 256;
          const int row = idx >> 6, cl = idx & 63, col = pp * 64 + cl;
          ev[pp * 4 + q2] = p.eps_q[((size_t)t * 64 + g2 * 16 + row) * 128 + col];
        }
      // GEMM1: x_prev @ Wxh (N=512)
      bf16x8 af1[4];
      if (t == 0) {
#pragma unroll
        for (int kt = 0; kt < 4; ++kt) af1[kt] = cvt8p(p.xq0 + kt * 32 + quad * 8);
      } else {
#pragma unroll
        for (int kt = 0; kt < 4; ++kt) af1[kt] = ldfrag(xql + l16 * 128 + kt * 32 + quad * 8);
      }
      f32x4 acc1[8] = {};
#pragma unroll
      for (int kt = 0; kt < 4; ++kt)
#pragma unroll
        for (int i = 0; i < 8; ++i) {
          bf16x8 bw = ldfrag(ldsWxh + ((size_t)((w * 8 + i) * 4 + kt) * 64 + lane) * 8);
          acc1[i] = MFMA16(af1[kt], bw, acc1[i]);
        }
      // h_c elementwise -> LDS
#pragma unroll
      for (int i = 0; i < 8; ++i) {
        const int ng = (w * 8 + i) * 16 + l16;
#pragma unroll
        for (int r = 0; r < 4; ++r) {
          const float u = acc1[i][r] + bx[i];
          const float e = __expf(2.f * u);
          const float th = 1.f - 2.f / (e + 1.f);
          const float hc = 0.5f * (th + bf2f(rv[i][r]));
          hcl[(quad * 4 + r) * 512 + ng] = f2bf(hc);
        }
      }
      __syncthreads();
      // GEMM2: h_c @ Wicat (N=256, K=512)
      bf16x8 af2[16];
#pragma unroll
      for (int kt = 0; kt < 16; ++kt) af2[kt] = ldfrag(hcl + l16 * 512 + kt * 32 + quad * 8);
      f32x4 acc2[4] = {};
#pragma unroll
      for (int kt = 0; kt < 16; ++kt)
#pragma unroll
        for (int i = 0; i < 4; ++i) acc2[i] = MFMA16(af2[kt], wbv[i][kt], acc2[i]);
      // write q_mu/q_lv directly; pair mu/lv via scr in two passes
#pragma unroll
      for (int i = 0; i < 4; ++i) {
        const int catcol = (w * 4 + i) * 16 + l16;
        const int within = catcol & 127, sub = within >> 6;
        const int col = (within & 63) + ((catcol >> 7) << 6);
        float* dbase = p.out + (sub ? QLV_O : QMU_O);
#pragma unroll
        for (int r = 0; r < 4; ++r) {
          const int b = g2 * 16 + quad * 4 + r;
          dbase[(size_t)b * 131072 + (size_t)t * 128 + col] = acc2[i][r] + bias2[i];
        }
      }
#pragma unroll
      for (int pp = 0; pp < 2; ++pp) {
        if ((w >> 1) == pp) {  // waves 0,1 -> pair0 ; waves 2,3 -> pair1
#pragma unroll
          for (int i = 0; i < 4; ++i) {
            const int catcol = (w * 4 + i) * 16 + l16;
            const int sub = (catcol >> 6) & 1, c6 = catcol & 63;
#pragma unroll
            for (int r = 0; r < 4; ++r)
              scr[(sub * 16 + quad * 4 + r) * 64 + c6] = acc2[i][r] + bias2[i];
          }
        }
        __syncthreads();
        {
#pragma unroll
          for (int q2 = 0; q2 < 4; ++q2) {
            const int idx = tid + q2 * 256;
            const int row = idx >> 6, cl = idx & 63, col = pp * 64 + cl;
            const int b = g2 * 16 + row;
            const float m = scr[row * 64 + cl], l = scr[(16 + row) * 64 + cl];
            const float xv = m + ev[pp * 4 + q2] * __expf(0.5f * l);
            p.out[QX_O + (size_t)b * 131072 + (size_t)t * 128 + col] = xv;
            const short xb = f2bf(xv);
            qxbf[((size_t)b * 1024 + t) * 128 + col] = xb;
            xql[row * 128 + col] = xb;
          }
        }
        __syncthreads();
      }
    }
    return;
  }

  // ---------------- gen crew: ZERO-HOP, 1 WG per group ----------------
  {
    const int g3 = wg - 72;
    // LDS: x [0,4096) | u1 [4096,36864) | pm [36864,40960) | Wmu [40960,73728) | Wlv [73728,106496)
    short* xl  = (short*)smem;
    short* u1l = (short*)(smem + 4096);
    short* pml = (short*)(smem + 36864);
    short* ldsWmu = (short*)(smem + 40960);
    short* ldsWlv = (short*)(smem + 73728);
    cpy16(smem + 40960, ws + OFF_WMU, 2048);
    cpy16(smem + 73728, ws + OFF_WLV, 2048);
    const short* w1cat = (const short*)(ws + OFF_W1CAT);
    const float* b1cat = (const float*)(ws + OFF_B1CAT);
    const short* wp2g = (const short*)(ws + OFF_WP2);
    const short* wg2g = (const short*)(ws + OFF_WG2);
    bf16x8 w1[16][4];
    float b1[16];
#pragma unroll
    for (int i = 0; i < 16; ++i) {
      const int nt = w * 16 + i;
#pragma unroll
      for (int kt = 0; kt < 4; ++kt)
        w1[i][kt] = ldfrag(w1cat + ((size_t)(nt * 4 + kt) * 64 + lane) * 8);
      b1[i] = b1cat[nt * 16 + l16];
    }
    float bp[2], bg[2], bm[2], bl[2];
#pragma unroll
    for (int i = 0; i < 2; ++i) {
      const int col = (w * 2 + i) * 16 + l16;
      bp[i] = p.bp2[col]; bg[i] = p.bg2[col]; bm[i] = p.bmu[col]; bl[i] = p.blv[col];
    }
    __syncthreads();
    for (int t = 0; t < 1024; ++t) {
      // eps_p prefetch for this thread's output cells
      float ep[2][4];
#pragma unroll
      for (int i = 0; i < 2; ++i) {
        const int col = (w * 2 + i) * 16 + l16;
#pragma unroll
        for (int r = 0; r < 4; ++r)
          ep[i][r] = p.eps_p[((size_t)t * 64 + g3 * 16 + quad * 4 + r) * 128 + col];
      }
      // P1: u1 = relu(x @ [Wg1|Wp1] + b1cat), N=1024
      bf16x8 ax[4];
      if (t == 0) {
#pragma unroll
        for (int kt = 0; kt < 4; ++kt) ax[kt] = cvt8p(p.x0 + kt * 32 + quad * 8);
      } else {
#pragma unroll
        for (int kt = 0; kt < 4; ++kt) ax[kt] = ldfrag(xl + l16 * 128 + kt * 32 + quad * 8);
      }
#pragma unroll
      for (int hf = 0; hf < 2; ++hf) {
        f32x4 a1[8] = {};
#pragma unroll
        for (int kt = 0; kt < 4; ++kt)
#pragma unroll
          for (int i = 0; i < 8; ++i) a1[i] = MFMA16(ax[kt], w1[hf * 8 + i][kt], a1[i]);
#pragma unroll
        for (int i = 0; i < 8; ++i) {
          const int c1 = (w * 16 + hf * 8 + i) * 16 + l16;
#pragma unroll
          for (int r = 0; r < 4; ++r) {
            const float u = a1[i][r] + b1[hf * 8 + i];
            u1l[(quad * 4 + r) * 1024 + c1] = f2bf(u > 0.f ? u : 0.f);
          }
        }
      }
      __syncthreads();
      // P2: pm = u1p@Wp2 (+bp2), gatepre = u1g@Wg2, xmu = x@Wmu  (Wp2/Wg2 streamed from L2)
      f32x4 apm[2] = {}, ag[2] = {}, axm[2] = {};
#pragma unroll
      for (int ch = 0; ch < 4; ++ch) {
        bf16x8 au[4], bwp[2][4];
#pragma unroll
        for (int kt = 0; kt < 4; ++kt)
          au[kt] = ldfrag(u1l + l16 * 1024 + 512 + (ch * 4 + kt) * 32 + quad * 8);
#pragma unroll
        for (int i = 0; i < 2; ++i)
#pragma unroll
          for (int kt = 0; kt < 4; ++kt)
            bwp[i][kt] = ldfrag(wp2g + ((size_t)((w * 2 + i) * 16 + ch * 4 + kt) * 64 + lane) * 8);
#pragma unroll
        for (int kt = 0; kt < 4; ++kt)
#pragma unroll
          for (int i = 0; i < 2; ++i) apm[i] = MFMA16(au[kt], bwp[i][kt], apm[i]);
      }
#pragma unroll
      for (int ch = 0; ch < 4; ++ch) {
        bf16x8 au[4], bwg[2][4];
#pragma unroll
        for (int kt = 0; kt < 4; ++kt)
          au[kt] = ldfrag(u1l + l16 * 1024 + (ch * 4 + kt) * 32 + quad * 8);
#pragma unroll
        for (int i = 0; i < 2; ++i)
#pragma unroll
          for (int kt = 0; kt < 4; ++kt)
            bwg[i][kt] = ldfrag(wg2g + ((size_t)((w * 2 + i) * 16 + ch * 4 + kt) * 64 + lane) * 8);
#pragma unroll
        for (int kt = 0; kt < 4; ++kt)
#pragma unroll
          for (int i = 0; i < 2; ++i) ag[i] = MFMA16(au[kt], bwg[i][kt], ag[i]);
      }
#pragma unroll
      for (int kt = 0; kt < 4; ++kt)
#pragma unroll
        for (int i = 0; i < 2; ++i) {
          bf16x8 bw = ldfrag(ldsWmu + ((size_t)((w * 2 + i) * 4 + kt) * 64 + lane) * 8);
          axm[i] = MFMA16(ax[kt], bw, axm[i]);
        }
      float pmv[2][4];
#pragma unroll
      for (int i = 0; i < 2; ++i) {
        const int col = (w * 2 + i) * 16 + l16;
#pragma unroll
        for (int r = 0; r < 4; ++r) {
          pmv[i][r] = apm[i][r] + bp[i];
          pml[(quad * 4 + r) * 128 + col] = f2bf(pmv[i][r]);
        }
      }
      __syncthreads();
      // P3: lv = relu(pm)@Wlv + blv; mu; sample; outputs
      bf16x8 apf[4];
#pragma unroll
      for (int kt = 0; kt < 4; ++kt)
        apf[kt] = relu8(ldfrag(pml + l16 * 128 + kt * 32 + quad * 8));
      f32x4 alv[2] = {};
#pragma unroll
      for (int kt = 0; kt < 4; ++kt)
#pragma unroll
        for (int i = 0; i < 2; ++i) {
          bf16x8 bw = ldfrag(ldsWlv + ((size_t)((w * 2 + i) * 4 + kt) * 64 + lane) * 8);
          alv[i] = MFMA16(apf[kt], bw, alv[i]);
        }
#pragma unroll
      for (int i = 0; i < 2; ++i) {
        const int col = (w * 2 + i) * 16 + l16;
#pragma unroll
        for (int r = 0; r < 4; ++r) {
          const int row = quad * 4 + r, b = g3 * 16 + row;
          const float lv = alv[i][r] + bl[i];
          const float gv = 1.f / (1.f + __expf(-(ag[i][r] + bg[i])));
          const float xmv = axm[i][r] + bm[i];
          const float mu = (1.f - gv) * xmv + gv * pmv[i][r];
          const float xv = mu + ep[i][r] * __expf(0.5f * lv);
          xl[row * 128 + col] = f2bf(xv);
          p.out[PMU_O + (size_t)b * 131072 + (size_t)t * 128 + col] = mu;
          p.out[PLV_O + (size_t)b * 131072 + (size_t)t * 128 + col] = lv;
          p.out[PX_O  + (size_t)b * 131072 + (size_t)t * 128 + col] = xv;
        }
      }
      __syncthreads();
    }
    return;
  }
}

// =====================================================================
// fused emission MLP: y = sigmoid(relu(relu(qx@W1+b1)@W2+b2)@W3+b3)
// =====================================================================
__global__ void __launch_bounds__(256) k_emis(P p) {
  extern __shared__ char smem[];
  short* h1 = (short*)smem;            // [64][520]
  short* h2 = (short*)(smem + 66560);  // [64][520]
  const int tid = threadIdx.x, lane = tid & 63, w = tid >> 6;
  const int l16 = lane & 15, quad = lane >> 4;
  const size_t m0 = (size_t)blockIdx.x * 64;
  const short* qx  = (const short*)(p.ws + OFF_QXBF);
  const short* ew1 = (const short*)(p.ws + OFF_EW1);
  const short* ew2 = (const short*)(p.ws + OFF_EW2);
  const short* ew3 = (const short*)(p.ws + OFF_EW3);
  for (int nc = 0; nc < 2; ++nc) {
    f32x4 acc[4][4] = {};
    for (int kt = 0; kt < 4; ++kt) {
      bf16x8 bw[4];
#pragma unroll
      for (int i = 0; i < 4; ++i) {
        const int nt = w * 8 + nc * 4 + i;
        bw[i] = ldfrag(ew1 + ((size_t)(nt * 4 + kt) * 64 + lane) * 8);
      }
#pragma unroll
      for (int mt = 0; mt < 4; ++mt) {
        bf16x8 af = ldfrag(qx + (m0 + mt * 16 + l16) * 128 + kt * 32 + quad * 8);
#pragma unroll
        for (int i = 0; i < 4; ++i) acc[mt][i] = MFMA16(af, bw[i], acc[mt][i]);
      }
    }
#pragma unroll
    for (int mt = 0; mt < 4; ++mt)
#pragma unroll
      for (int i = 0; i < 4; ++i) {
        const int col = (w * 8 + nc * 4 + i) * 16 + l16;
        const float bias = p.eb1[col];
#pragma unroll
        for (int r = 0; r < 4; ++r) {
          const float v = acc[mt][i][r] + bias;
          h1[(mt * 16 + quad * 4 + r) * 520 + col] = f2bf(v > 0.f ? v : 0.f);
        }
      }
  }
  __syncthreads();
  for (int nc = 0; nc < 2; ++nc) {
    f32x4 acc[4][4] = {};
    for (int kt = 0; kt < 16; ++kt) {
      bf16x8 bw[4];
#pragma unroll
      for (int i = 0; i < 4; ++i) {
        const int nt = w * 8 + nc * 4 + i;
        bw[i] = ldfrag(ew2 + ((size_t)(nt * 16 + kt) * 64 + lane) * 8);
      }
#pragma unroll
      for (int mt = 0; mt < 4; ++mt) {
        bf16x8 af = ldfrag(h1 + (mt * 16 + l16) * 520 + kt * 32 + quad * 8);
#pragma unroll
        for (int i = 0; i < 4; ++i) acc[mt][i] = MFMA16(af, bw[i], acc[mt][i]);
      }
    }
#pragma unroll
    for (int mt = 0; mt < 4; ++mt)
#pragma unroll
      for (int i = 0; i < 4; ++i) {
        const int col = (w * 8 + nc * 4 + i) * 16 + l16;
        const float bias = p.eb2[col];
#pragma unroll
        for (int r = 0; r < 4; ++r) {
          const float v = acc[mt][i][r] + bias;
          h2[(mt * 16 + quad * 4 + r) * 520 + col] = f2bf(v > 0.f ? v : 0.f);
        }
      }
  }
  __syncthreads();
  for (int nc = 0; nc < 2; ++nc) {
    f32x4 acc[4][4] = {};
    for (int kt = 0; kt < 16; ++kt) {
      bf16x8 bw[4];
#pragma unroll
      for (int i = 0; i < 4; ++i) {
        const int nt = w * 8 + nc * 4 + i;
        bw[i] = ldfrag(ew3 + ((size_t)(nt * 16 + kt) * 64 + lane) * 8);
      }
#pragma unroll
      for (int mt = 0; mt < 4; ++mt) {
        bf16x8 af = ldfrag(h2 + (mt * 16 + l16) * 520 + kt * 32 + quad * 8);
#pragma unroll
        for (int i = 0; i < 4; ++i) acc[mt][i] = MFMA16(af, bw[i], acc[mt][i]);
      }
    }
#pragma unroll
    for (int mt = 0; mt < 4; ++mt)
#pragma unroll
      for (int i = 0; i < 4; ++i) {
        const int col = (w * 8 + nc * 4 + i) * 16 + l16;
        const float bias = p.eb3[col];
#pragma unroll
        for (int r = 0; r < 4; ++r) {
          const size_t m = m0 + mt * 16 + quad * 4 + r;
          const size_t b = m >> 10, tt2 = m & 1023;
          const float v = acc[mt][i][r] + bias;
          p.out[Y_O + (b << 19) + tt2 * 512 + col] = 1.f / (1.f + __expf(-v));
        }
      }
  }
}

extern "C" void kernel_launch(void* const* d_in, const int* in_sizes, int n_in,
                              void* d_out, int out_size, void* d_ws, size_t ws_size,
                              hipStream_t stream) {
  (void)in_sizes; (void)n_in; (void)out_size; (void)ws_size;
  P p;
  p.ws = (char*)d_ws; p.out = (float*)d_out;
  p.data = (const float*)d_in[0];
  p.eps_q = (const float*)d_in[1];
  p.eps_p = (const float*)d_in[2];
  p.Wih = (const float*)d_in[3]; p.Whh = (const float*)d_in[4];
  p.bih = (const float*)d_in[5]; p.bhh = (const float*)d_in[6];
  p.h0 = (const float*)d_in[7]; p.xq0 = (const float*)d_in[8]; p.x0 = (const float*)d_in[9];
  p.Wxh = (const float*)d_in[10]; p.bxh = (const float*)d_in[11];
  p.Whm = (const float*)d_in[12]; p.bhm = (const float*)d_in[13];
  p.Whl = (const float*)d_in[14]; p.bhl = (const float*)d_in[15];
  p.Wg1 = (const float*)d_in[16]; p.bg1 = (const float*)d_in[17];
  p.Wg2 = (const float*)d_in[18]; p.bg2 = (const float*)d_in[19];
  p.Wp1 = (const float*)d_in[20]; p.bp1 = (const float*)d_in[21];
  p.Wp2 = (const float*)d_in[22]; p.bp2 = (const float*)d_in[23];
  p.Wmu = (const float*)d_in[24]; p.bmu = (const float*)d_in[25];
  p.Wlv = (const float*)d_in[26]; p.blv = (const float*)d_in[27];
  p.eW1 = (const float*)d_in[28]; p.eb1 = (const float*)d_in[29];
  p.eW2 = (const float*)d_in[30]; p.eb2 = (const float*)d_in[31];
  p.eW3 = (const float*)d_in[32]; p.eb3 = (const float*)d_in[33];

  hipFuncSetAttribute(reinterpret_cast<const void*>(k_scan),
                      hipFuncAttributeMaxDynamicSharedMemorySize, SMEM_SCAN);
  hipFuncSetAttribute(reinterpret_cast<const void*>(k_emis),
                      hipFuncAttributeMaxDynamicSharedMemorySize, SMEM_EMIS);

  k_prep<<<dim3(2048), dim3(256), 0, stream>>>(p);
  k_scan<<<dim3(76), dim3(256), SMEM_SCAN, stream>>>(p);
  k_emis<<<dim3(1024), dim3(256), SMEM_EMIS, stream>>>(p);
}

// Round 5
// 12993.547 us; speedup vs baseline: 2.5567x; 1.0685x over previous
//
#include <hip/hip_runtime.h>
#include <stdint.h>

typedef __bf16 bf16x8 __attribute__((ext_vector_type(8)));
typedef short  s16x8  __attribute__((ext_vector_type(8)));
typedef float  f32x4  __attribute__((ext_vector_type(4)));

#define MFMA16(a, b, c) __builtin_amdgcn_mfma_f32_16x16x32_bf16((a), (b), (c), 0, 0, 0)

// ---------------- workspace layout (bytes) ----------------
#define OFF_X      0ull          // (T,64,512) bf16: xp, overwritten by h (history)
#define OFF_QXBF   67108864ull   // (B,T,128) bf16 copy of q_x for emission
#define OFF_WIH    83886080ull
#define OFF_WHH    84410368ull
#define OFF_WXH    84934656ull
#define OFF_WICAT  85065728ull   // [Whm|Whl] interleaved 64-col blocks, N=256
#define OFF_W1CAT  85327872ull   // [Wg1|Wp1], N=1024
#define OFF_WG2    85590016ull
#define OFF_WP2    85721088ull
#define OFF_WMU    85852160ull
#define OFF_WLV    85884928ull
#define OFF_EW1    85917696ull
#define OFF_EW2    86048768ull
#define OFF_EW3    86573056ull
#define OFF_B1CAT  87097344ull   // fp32 [1024]
#define OFF_BICAT  87101440ull   // fp32 [256]
#define OFF_XPCNT  87364608ull   // int[1024]

// ---------------- d_out offsets (floats) ----------------
#define QX_O  0ull
#define QMU_O 8388608ull
#define QLV_O 16777216ull
#define PX_O  25165824ull
#define PMU_O 33554432ull
#define PLV_O 41943040ull
#define Y_O   50331648ull

#define SMEM_SCAN 131072
#define SMEM_EMIS 133120

struct P {
  char* ws; float* out;
  const float *data, *eps_q, *eps_p;
  const float *Wih, *Whh, *bih, *bhh, *h0, *xq0, *x0;
  const float *Wxh, *bxh, *Whm, *bhm, *Whl, *bhl;
  const float *Wg1, *bg1, *Wg2, *bg2, *Wp1, *bp1, *Wp2, *bp2, *Wmu, *bmu, *Wlv, *blv;
  const float *eW1, *eb1, *eW2, *eb2, *eW3, *eb3;
};

__device__ __forceinline__ short f2bf(float f) {
  union { float f; uint32_t u; } v; v.f = f;
  uint32_t r = (v.u + 0x7FFFu + ((v.u >> 16) & 1u)) >> 16;
  return (short)(uint16_t)r;
}
__device__ __forceinline__ float bf2f(short s) {
  union { uint32_t u; float f; } v; v.u = ((uint32_t)(uint16_t)s) << 16;
  return v.f;
}
__device__ __forceinline__ bf16x8 ldfrag(const short* pp) { return *(const bf16x8*)pp; }
__device__ __forceinline__ bf16x8 cvt8p(const float* pp) {
  bf16x8 r;
#pragma unroll
  for (int i = 0; i < 8; ++i) r[i] = (__bf16)pp[i];
  return r;
}
__device__ __forceinline__ bf16x8 relu8(bf16x8 a) {
  s16x8 s = __builtin_bit_cast(s16x8, a);
#pragma unroll
  for (int i = 0; i < 8; ++i) s[i] = (s[i] < 0) ? (short)0 : s[i];
  return __builtin_bit_cast(bf16x8, s);
}

// -------- agent-scope (sc1, L2-bypass) communication primitives --------
__device__ __forceinline__ void relfence() {
  asm volatile("s_waitcnt vmcnt(0)" ::: "memory");
}
__device__ __forceinline__ void st_sc16(short* pp, short v) {
  __hip_atomic_store(pp, v, __ATOMIC_RELAXED, __HIP_MEMORY_SCOPE_AGENT);
}
__device__ __forceinline__ short ld_sc16(const short* pp) {
  return __hip_atomic_load((short*)pp, __ATOMIC_RELAXED, __HIP_MEMORY_SCOPE_AGENT);
}
__device__ __forceinline__ int ldflag(int* pp) {
  return __hip_atomic_load(pp, __ATOMIC_RELAXED, __HIP_MEMORY_SCOPE_AGENT);
}
// LDS-only barrier: orders ds ops across the WG WITHOUT draining vmcnt.
__device__ __forceinline__ void barrier_lgkm() {
  __builtin_amdgcn_sched_barrier(0);
  asm volatile("s_waitcnt lgkmcnt(0)" ::: "memory");
  __builtin_amdgcn_s_barrier();
  __builtin_amdgcn_sched_barrier(0);
}

// pack W (K x N, row-major fp32) into MFMA-B fragment order:
// dst[((nt*KT+kt)*64+lane)*8+j] = W[kt*32+(lane>>4)*8+j][nt*16+(lane&15)]
__device__ __forceinline__ void pack_w(short* dst, const float* src, int KT, int N, int idx) {
  int tile = idx >> 9, rem = idx & 511;
  int lane = rem >> 3, j = rem & 7;
  int nt = tile / KT, kt = tile - nt * KT;
  int k = kt * 32 + ((lane >> 4) << 3) + j, n = (nt << 4) + (lane & 15);
  dst[idx] = f2bf(src[(int64_t)k * N + n]);
}

__global__ void __launch_bounds__(256) k_prep(P p) {
  char* ws = p.ws;
  const int64_t total = 1608032;
  for (int64_t i = (int64_t)blockIdx.x * 256 + threadIdx.x; i < total;
       i += (int64_t)gridDim.x * 256) {
    int64_t r = i;
    if (r < 262144) { pack_w((short*)(ws + OFF_WIH), p.Wih, 16, 512, (int)r); continue; }
    r -= 262144;
    if (r < 262144) { pack_w((short*)(ws + OFF_WHH), p.Whh, 16, 512, (int)r); continue; }
    r -= 262144;
    if (r < 65536) { pack_w((short*)(ws + OFF_WXH), p.Wxh, 4, 512, (int)r); continue; }
    r -= 65536;
    if (r < 131072) {  // Wicat
      int idx = (int)r;
      int tile = idx >> 9, rem = idx & 511, lane = rem >> 3, jj = rem & 7;
      int nt = tile >> 4, kt = tile & 15;
      int k = kt * 32 + ((lane >> 4) << 3) + jj, ccol = (nt << 4) + (lane & 15);
      int pair = ccol >> 7, within = ccol & 127, sub = within >> 6;
      int col = (within & 63) + (pair << 6);
      const float* s = sub ? p.Whl : p.Whm;
      ((short*)(ws + OFF_WICAT))[idx] = f2bf(s[(int64_t)k * 128 + col]);
      continue;
    }
    r -= 131072;
    if (r < 131072) {  // W1cat = [Wg1|Wp1]
      int idx = (int)r;
      int tile = idx >> 9, rem = idx & 511, lane = rem >> 3, jj = rem & 7;
      int nt = tile >> 2, kt = tile & 3;
      int k = kt * 32 + ((lane >> 4) << 3) + jj, ccol = (nt << 4) + (lane & 15);
      const float* s = (ccol < 512) ? p.Wg1 : p.Wp1;
      ((short*)(ws + OFF_W1CAT))[idx] = f2bf(s[(int64_t)k * 512 + (ccol & 511)]);
      continue;
    }
    r -= 131072;
    if (r < 65536) { pack_w((short*)(ws + OFF_WG2), p.Wg2, 16, 128, (int)r); continue; }
    r -= 65536;
    if (r < 65536) { pack_w((short*)(ws + OFF_WP2), p.Wp2, 16, 128, (int)r); continue; }
    r -= 65536;
    if (r < 16384) { pack_w((short*)(ws + OFF_WMU), p.Wmu, 4, 128, (int)r); continue; }
    r -= 16384;
    if (r < 16384) { pack_w((short*)(ws + OFF_WLV), p.Wlv, 4, 128, (int)r); continue; }
    r -= 16384;
    if (r < 65536) { pack_w((short*)(ws + OFF_EW1), p.eW1, 4, 512, (int)r); continue; }
    r -= 65536;
    if (r < 262144) { pack_w((short*)(ws + OFF_EW2), p.eW2, 16, 512, (int)r); continue; }
    r -= 262144;
    if (r < 262144) { pack_w((short*)(ws + OFF_EW3), p.eW3, 16, 512, (int)r); continue; }
    r -= 262144;
    if (r < 1024) { ((float*)(ws + OFF_B1CAT))[r] = (r < 512) ? p.bg1[r] : p.bp1[r - 512]; continue; }
    r -= 1024;
    if (r < 256) {
      int ccol = (int)r; int pair = ccol >> 7, within = ccol & 127, sub = within >> 6;
      int col = (within & 63) + (pair << 6);
      ((float*)(ws + OFF_BICAT))[ccol] = sub ? p.bhl[col] : p.bhm[col];
      continue;
    }
    r -= 256;
    ((int*)(ws + OFF_XPCNT))[r] = 0;  // flags
  }
}

// =====================================================================
// persistent scan kernel: 72 WGs x 512 threads, ZERO cross-WG hops in
// all recurrences (only xproj->RNN uses a pipelined progress counter).
//   [0,64):  xproj crew
//   [64,68): RNN crew (1 WG/group; Whh 13kt regs + 3kt LDS (96KB),
//            h double-buffered 2x16KB) -> re-roles to inf crew
//   [68,72): gen crew (1 WG/group; W1cat regs, Wg2+Wp2 streamed from L2,
//            Wmu/Wlv in LDS)
// LDS capped at 128KB; VGPR budgeted <=256/wave on every path.
// =====================================================================
__global__ void __launch_bounds__(512, 2) k_scan(P p) {
  extern __shared__ char smem[];
  char* ws = p.ws;
  const int tid = threadIdx.x;
  const int lane = tid & 63, w = tid >> 6;
  const int l16 = lane & 15, quad = lane >> 4;
  const int wg = blockIdx.x;

  short* Xb   = (short*)(ws + OFF_X);
  short* qxbf = (short*)(ws + OFF_QXBF);
  int* xp_cnt = (int*)(ws + OFF_XPCNT);

  if (wg < 64) {
    // ---------------- xproj crew ----------------
    const int s = wg & 7, t0 = wg >> 3;
    const int mrow4 = (w & 3) * 16;
    const int nt0 = s * 4 + (w >> 2) * 2;
    const short* wih = (const short*)(ws + OFF_WIH);
    for (int tt = 0; tt < 128; ++tt) {
      const int t = t0 + (tt << 3);
      const int tsrc = 1023 - t;
      const float* arow = p.data + ((size_t)(mrow4 + l16) * 1024 + tsrc) * 512 + quad * 8;
      f32x4 acc[2] = {};
      for (int kt = 0; kt < 16; ++kt) {
        bf16x8 af = cvt8p(arow + kt * 32);
#pragma unroll
        for (int i = 0; i < 2; ++i) {
          bf16x8 bw = ldfrag(wih + ((size_t)((nt0 + i) * 16 + kt) * 64 + lane) * 8);
          acc[i] = MFMA16(af, bw, acc[i]);
        }
      }
      short* xrow = Xb + (size_t)t * 32768;
#pragma unroll
      for (int i = 0; i < 2; ++i) {
        const int col = (nt0 + i) * 16 + l16;
        const float bias = p.bih[col] + p.bhh[col];
#pragma unroll
        for (int r = 0; r < 4; ++r) {
          const int row = mrow4 + quad * 4 + r;
          st_sc16(xrow + (size_t)row * 512 + col, f2bf(acc[i][r] + bias));
        }
      }
      relfence();
      __syncthreads();
      if (tid == 0) atomicAdd(xp_cnt + t, 1);
    }
    return;
  }

  if (wg < 68) {
    // ---------------- RNN crew: one WG per group, zero hops ----------
    const int g = wg - 64;
    short* whh_l = (short*)smem;            // kt 13..15 frags, 96 KB
    char* hbuf = smem + 98304;              // [2][16][512] bf16 swizzled
    {
      const float4* src4 = (const float4*)(ws + OFF_WHH);
      float4* dst4 = (float4*)smem;
      for (int i2 = tid; i2 < 6144; i2 += 512) {
        const int blk = i2 >> 6, wi = i2 & 63;
        const int nt = blk / 3, kk = blk - nt * 3;
        dst4[(size_t)blk * 64 + wi] = src4[(size_t)(nt * 16 + 13 + kk) * 64 + wi];
      }
    }
    const short* whh = (const short*)(ws + OFF_WHH);
    bf16x8 wb[4][13];
#pragma unroll
    for (int i = 0; i < 4; ++i) {
      const int nt = w * 4 + i;
#pragma unroll
      for (int kt = 0; kt < 13; ++kt)
        wb[i][kt] = ldfrag(whh + ((size_t)(nt * 16 + kt) * 64 + lane) * 8);
    }
    __syncthreads();
    // -------- t = 0 peeled --------
    while (ldflag(xp_cnt) < 8) __builtin_amdgcn_s_sleep(2);
    short xv[4][4];
#pragma unroll
    for (int i = 0; i < 4; ++i) {
      const int col = (w * 4 + i) * 16 + l16;
#pragma unroll
      for (int r = 0; r < 4; ++r)
        xv[i][r] = ld_sc16(Xb + (size_t)(g * 16 + quad * 4 + r) * 512 + col);
    }
    {
      f32x4 acc[4] = {};
#pragma unroll
      for (int c = 0; c < 8; ++c) {
        bf16x8 a2[2];
#pragma unroll
        for (int k2 = 0; k2 < 2; ++k2) a2[k2] = cvt8p(p.h0 + (c * 2 + k2) * 32 + quad * 8);
#pragma unroll
        for (int k2 = 0; k2 < 2; ++k2) {
          const int kt = c * 2 + k2;
#pragma unroll
          for (int i = 0; i < 4; ++i) {
            bf16x8 bw = (kt < 13)
                ? wb[i][kt]
                : ldfrag(whh_l + ((size_t)((w * 4 + i) * 3 + (kt - 13)) * 64 + lane) * 8);
            acc[i] = MFMA16(a2[k2], bw, acc[i]);
          }
        }
      }
      char* hw = hbuf;  // buffer 0
      short* xrow = Xb;
#pragma unroll
      for (int i = 0; i < 4; ++i) {
        const int col = (w * 4 + i) * 16 + l16;
#pragma unroll
        for (int r = 0; r < 4; ++r) {
          const int row = quad * 4 + r;
          float h = acc[i][r] + bf2f(xv[i][r]);
          const short hv = f2bf(h > 0.f ? h : 0.f);
          *(short*)(hw + row * 1024 + ((col * 2) ^ ((row & 7) << 4))) = hv;
          st_sc16(xrow + (size_t)(g * 16 + row) * 512 + col, hv);
        }
      }
      // prefetch xp(1)
      while (ldflag(xp_cnt + 1) < 8) __builtin_amdgcn_s_sleep(2);
      const short* xn = Xb + 32768;
#pragma unroll
      for (int i = 0; i < 4; ++i) {
        const int col = (w * 4 + i) * 16 + l16;
#pragma unroll
        for (int r = 0; r < 4; ++r)
          xv[i][r] = ld_sc16(xn + (size_t)(g * 16 + quad * 4 + r) * 512 + col);
      }
      barrier_lgkm();
    }
    // -------- t = 1..1023 --------
    for (int t = 1; t < 1024; ++t) {
      const char* hb = hbuf + ((t - 1) & 1) * 16384;
      f32x4 acc[4] = {};
#pragma unroll
      for (int c = 0; c < 8; ++c) {
        bf16x8 a2[2];
#pragma unroll
        for (int k2 = 0; k2 < 2; ++k2) {
          const int kt = c * 2 + k2;
          a2[k2] = ldfrag((const short*)(hb + l16 * 1024 +
                     ((kt * 64 + quad * 16) ^ ((l16 & 7) << 4))));
        }
#pragma unroll
        for (int k2 = 0; k2 < 2; ++k2) {
          const int kt = c * 2 + k2;
#pragma unroll
          for (int i = 0; i < 4; ++i) {
            bf16x8 bw = (kt < 13)
                ? wb[i][kt]
                : ldfrag(whh_l + ((size_t)((w * 4 + i) * 3 + (kt - 13)) * 64 + lane) * 8);
            acc[i] = MFMA16(a2[k2], bw, acc[i]);
          }
        }
      }
      char* hw = hbuf + (t & 1) * 16384;
      short* xrow = Xb + (size_t)t * 32768;
#pragma unroll
      for (int i = 0; i < 4; ++i) {
        const int col = (w * 4 + i) * 16 + l16;
#pragma unroll
        for (int r = 0; r < 4; ++r) {
          const int row = quad * 4 + r;
          float h = acc[i][r] + bf2f(xv[i][r]);
          const short hv = f2bf(h > 0.f ? h : 0.f);
          *(short*)(hw + row * 1024 + ((col * 2) ^ ((row & 7) << 4))) = hv;
          st_sc16(xrow + (size_t)(g * 16 + row) * 512 + col, hv);
        }
      }
      if (t < 1023) {
        int* fc = xp_cnt + t + 1;
        while (ldflag(fc) < 8) __builtin_amdgcn_s_sleep(2);
        const short* xn = Xb + (size_t)(t + 1) * 32768;
#pragma unroll
        for (int i = 0; i < 4; ++i) {
          const int col = (w * 4 + i) * 16 + l16;
#pragma unroll
          for (int r = 0; r < 4; ++r)
            xv[i][r] = ld_sc16(xn + (size_t)(g * 16 + quad * 4 + r) * 512 + col);
        }
      }
      barrier_lgkm();
    }
    // ---------------- re-role: zero-hop inf crew ----------------
    relfence();
    __syncthreads();
    const int g2 = g;
    char* hcs = smem;                     // [16][512] bf16 swz
    char* xqs = smem + 16384;             // [16][128] bf16 swz
    float* scr = (float*)(smem + 20480);  // [2][16][128] f32
    const short* wxh = (const short*)(ws + OFF_WXH);
    const short* wicat = (const short*)(ws + OFF_WICAT);
    const float* bicat = (const float*)(ws + OFF_BICAT);
    bf16x8 wa[4][4];
    float bx[4];
#pragma unroll
    for (int i = 0; i < 4; ++i) {
      const int nt = w * 4 + i;
#pragma unroll
      for (int kt = 0; kt < 4; ++kt)
        wa[i][kt] = ldfrag(wxh + ((size_t)(nt * 4 + kt) * 64 + lane) * 8);
      bx[i] = p.bxh[nt * 16 + l16];
    }
    bf16x8 wbv[2][16];
    float bias2[2];
#pragma unroll
    for (int i = 0; i < 2; ++i) {
      const int nt = w * 2 + i;
#pragma unroll
      for (int kt = 0; kt < 16; ++kt)
        wbv[i][kt] = ldfrag(wicat + ((size_t)(nt * 16 + kt) * 64 + lane) * 8);
      bias2[i] = bicat[nt * 16 + l16];
    }
    for (int t = 0; t < 1024; ++t) {
      short rv[4][4];
      const short* rsrc = Xb + (size_t)(1023 - t) * 32768;
#pragma unroll
      for (int i = 0; i < 4; ++i) {
        const int ng = (w * 4 + i) * 16 + l16;
#pragma unroll
        for (int r = 0; r < 4; ++r)
          rv[i][r] = ld_sc16(rsrc + (size_t)(g2 * 16 + quad * 4 + r) * 512 + ng);
      }
      float ev[4];
#pragma unroll
      for (int q2 = 0; q2 < 4; ++q2) {
        const int idx = tid + q2 * 512;
        const int row = idx >> 7, cl = idx & 127;
        ev[q2] = p.eps_q[((size_t)t * 64 + g2 * 16 + row) * 128 + cl];
      }
      // GEMM1: x_prev @ Wxh
      bf16x8 af1[4];
      if (t == 0) {
#pragma unroll
        for (int kt = 0; kt < 4; ++kt) af1[kt] = cvt8p(p.xq0 + kt * 32 + quad * 8);
      } else {
#pragma unroll
        for (int kt = 0; kt < 4; ++kt)
          af1[kt] = ldfrag((const short*)(xqs + l16 * 256 +
                     ((kt * 64 + quad * 16) ^ ((l16 & 7) << 4))));
      }
      f32x4 acc1[4] = {};
#pragma unroll
      for (int kt = 0; kt < 4; ++kt)
#pragma unroll
        for (int i = 0; i < 4; ++i) acc1[i] = MFMA16(af1[kt], wa[i][kt], acc1[i]);
#pragma unroll
      for (int i = 0; i < 4; ++i) {
        const int ng = (w * 4 + i) * 16 + l16;
#pragma unroll
        for (int r = 0; r < 4; ++r) {
          const int row = quad * 4 + r;
          const float u = acc1[i][r] + bx[i];
          const float e = __expf(2.f * u);
          const float th = 1.f - 2.f / (e + 1.f);
          const float hcv = 0.5f * (th + bf2f(rv[i][r]));
          *(short*)(hcs + row * 1024 + ((ng * 2) ^ ((row & 7) << 4))) = f2bf(hcv);
        }
      }
      barrier_lgkm();
      // GEMM2: h_c @ Wicat
      f32x4 acc2[2] = {};
#pragma unroll
      for (int c = 0; c < 4; ++c) {
        bf16x8 a4[4];
#pragma unroll
        for (int k2 = 0; k2 < 4; ++k2) {
          const int kt = c * 4 + k2;
          a4[k2] = ldfrag((const short*)(hcs + l16 * 1024 +
                     ((kt * 64 + quad * 16) ^ ((l16 & 7) << 4))));
        }
#pragma unroll
        for (int k2 = 0; k2 < 4; ++k2)
#pragma unroll
          for (int i = 0; i < 2; ++i) acc2[i] = MFMA16(a4[k2], wbv[i][c * 4 + k2], acc2[i]);
      }
#pragma unroll
      for (int i = 0; i < 2; ++i) {
        const int catcol = (w * 2 + i) * 16 + l16;
        const int within = catcol & 127, sub = within >> 6;
        const int col = (within & 63) + ((catcol >> 7) << 6);
        float* dbase = p.out + (sub ? QLV_O : QMU_O);
#pragma unroll
        for (int r = 0; r < 4; ++r) {
          const int row = quad * 4 + r;
          const float v = acc2[i][r] + bias2[i];
          dbase[(size_t)(g2 * 16 + row) * 131072 + (size_t)t * 128 + col] = v;
          scr[(sub * 16 + row) * 128 + col] = v;
        }
      }
      barrier_lgkm();
      // sample
#pragma unroll
      for (int q2 = 0; q2 < 4; ++q2) {
        const int idx = tid + q2 * 512;
        const int row = idx >> 7, cl = idx & 127;
        const int b = g2 * 16 + row;
        const float m = scr[row * 128 + cl], l = scr[(16 + row) * 128 + cl];
        const float xvv = m + ev[q2] * __expf(0.5f * l);
        p.out[QX_O + (size_t)b * 131072 + (size_t)t * 128 + cl] = xvv;
        const short xb = f2bf(xvv);
        qxbf[((size_t)b * 1024 + t) * 128 + cl] = xb;
        *(short*)(xqs + row * 256 + ((cl * 2) ^ ((row & 7) << 4))) = xb;
      }
      barrier_lgkm();
    }
    return;
  }

  // ---------------- gen crew: one WG per group, zero hops ----------------
  {
    const int g3 = wg - 68;
    short* ldsWmu = (short*)smem;              // 32 KB frag-order
    short* ldsWlv = (short*)(smem + 32768);    // 32 KB
    char* xls  = smem + 65536;                 // [16][128] bf16 swz
    char* u1ls = smem + 69632;                 // [16][1024] bf16 swz
    char* pmls = smem + 102400;                // [16][128] bf16 swz
    {
      const float4* s1 = (const float4*)(ws + OFF_WMU);
      const float4* s2 = (const float4*)(ws + OFF_WLV);
      float4* d1 = (float4*)smem;
      float4* d2 = (float4*)(smem + 32768);
      for (int i2 = tid; i2 < 2048; i2 += 512) { d1[i2] = s1[i2]; d2[i2] = s2[i2]; }
    }
    const short* w1cat = (const short*)(ws + OFF_W1CAT);
    const float* b1cat = (const float*)(ws + OFF_B1CAT);
    const short* wp2g = (const short*)(ws + OFF_WP2);
    const short* wg2g = (const short*)(ws + OFF_WG2);
    bf16x8 w1[8][4];
    float b1[8];
#pragma unroll
    for (int i = 0; i < 8; ++i) {
      const int nt = w * 8 + i;
#pragma unroll
      for (int kt = 0; kt < 4; ++kt)
        w1[i][kt] = ldfrag(w1cat + ((size_t)(nt * 4 + kt) * 64 + lane) * 8);
      b1[i] = b1cat[nt * 16 + l16];
    }
    const int colw = w * 16 + l16;
    const float bpv = p.bp2[colw], bgv = p.bg2[colw], bmv = p.bmu[colw], blvv = p.blv[colw];
    __syncthreads();
    for (int t = 0; t < 1024; ++t) {
      float ep[4];
#pragma unroll
      for (int r = 0; r < 4; ++r)
        ep[r] = p.eps_p[((size_t)t * 64 + g3 * 16 + quad * 4 + r) * 128 + colw];
      // P1: u1 = relu(x @ [Wg1|Wp1] + b1)
      bf16x8 ax[4];
      if (t == 0) {
#pragma unroll
        for (int kt = 0; kt < 4; ++kt) ax[kt] = cvt8p(p.x0 + kt * 32 + quad * 8);
      } else {
#pragma unroll
        for (int kt = 0; kt < 4; ++kt)
          ax[kt] = ldfrag((const short*)(xls + l16 * 256 +
                     ((kt * 64 + quad * 16) ^ ((l16 & 7) << 4))));
      }
#pragma unroll
      for (int hf = 0; hf < 2; ++hf) {
        f32x4 a1[4] = {};
#pragma unroll
        for (int kt = 0; kt < 4; ++kt)
#pragma unroll
          for (int i = 0; i < 4; ++i) a1[i] = MFMA16(ax[kt], w1[hf * 4 + i][kt], a1[i]);
#pragma unroll
        for (int i = 0; i < 4; ++i) {
          const int c1 = (w * 8 + hf * 4 + i) * 16 + l16;
#pragma unroll
          for (int r = 0; r < 4; ++r) {
            const int row = quad * 4 + r;
            const float u = a1[i][r] + b1[hf * 4 + i];
            *(short*)(u1ls + row * 2048 + ((c1 * 2) ^ ((row & 7) << 4))) = f2bf(u > 0.f ? u : 0.f);
          }
        }
      }
      barrier_lgkm();
      // P2: pm (Wp2 streamed), gate (Wg2 streamed), xmu (LDS Wmu)
      f32x4 apm = {}, ag = {}, axm = {};
#pragma unroll
      for (int c = 0; c < 8; ++c) {
        bf16x8 bpf[2], bgf[2];
#pragma unroll
        for (int k2 = 0; k2 < 2; ++k2) {
          bpf[k2] = ldfrag(wp2g + ((size_t)(w * 16 + c * 2 + k2) * 64 + lane) * 8);
          bgf[k2] = ldfrag(wg2g + ((size_t)(w * 16 + c * 2 + k2) * 64 + lane) * 8);
        }
        bf16x8 aup[2], aug[2];
#pragma unroll
        for (int k2 = 0; k2 < 2; ++k2) {
          const int kt = c * 2 + k2;
          aup[k2] = ldfrag((const short*)(u1ls + l16 * 2048 +
                      ((1024 + kt * 64 + quad * 16) ^ ((l16 & 7) << 4))));
          aug[k2] = ldfrag((const short*)(u1ls + l16 * 2048 +
                      ((kt * 64 + quad * 16) ^ ((l16 & 7) << 4))));
        }
#pragma unroll
        for (int k2 = 0; k2 < 2; ++k2) {
          apm = MFMA16(aup[k2], bpf[k2], apm);
          ag  = MFMA16(aug[k2], bgf[k2], ag);
        }
      }
#pragma unroll
      for (int kt = 0; kt < 4; ++kt) {
        bf16x8 bw = ldfrag(ldsWmu + ((size_t)(w * 4 + kt) * 64 + lane) * 8);
        axm = MFMA16(ax[kt], bw, axm);
      }
      float pmv[4];
#pragma unroll
      for (int r = 0; r < 4; ++r) {
        const int row = quad * 4 + r;
        pmv[r] = apm[r] + bpv;
        *(short*)(pmls + row * 256 + ((colw * 2) ^ ((row & 7) << 4))) = f2bf(pmv[r]);
      }
      barrier_lgkm();
      // P3: lv = relu(pm)@Wlv; mu; sample; outputs
      bf16x8 apf[4];
#pragma unroll
      for (int kt = 0; kt < 4; ++kt)
        apf[kt] = relu8(ldfrag((const short*)(pmls + l16 * 256 +
                    ((kt * 64 + quad * 16) ^ ((l16 & 7) << 4)))));
      f32x4 alv = {};
#pragma unroll
      for (int kt = 0; kt < 4; ++kt) {
        bf16x8 bw = ldfrag(ldsWlv + ((size_t)(w * 4 + kt) * 64 + lane) * 8);
        alv = MFMA16(apf[kt], bw, alv);
      }
#pragma unroll
      for (int r = 0; r < 4; ++r) {
        const int row = quad * 4 + r, b = g3 * 16 + row;
        const float lv = alv[r] + blvv;
        const float gv = 1.f / (1.f + __expf(-(ag[r] + bgv)));
        const float xmv = axm[r] + bmv;
        const float mu = (1.f - gv) * xmv + gv * pmv[r];
        const float xvv = mu + ep[r] * __expf(0.5f * lv);
        *(short*)(xls + row * 256 + ((colw * 2) ^ ((row & 7) << 4))) = f2bf(xvv);
        p.out[PMU_O + (size_t)b * 131072 + (size_t)t * 128 + colw] = mu;
        p.out[PLV_O + (size_t)b * 131072 + (size_t)t * 128 + colw] = lv;
        p.out[PX_O  + (size_t)b * 131072 + (size_t)t * 128 + colw] = xvv;
      }
      barrier_lgkm();
    }
    return;
  }
}

// =====================================================================
// fused emission MLP: y = sigmoid(relu(relu(qx@W1+b1)@W2+b2)@W3+b3)
// =====================================================================
__global__ void __launch_bounds__(256) k_emis(P p) {
  extern __shared__ char smem[];
  short* h1 = (short*)smem;            // [64][520]
  short* h2 = (short*)(smem + 66560);  // [64][520]
  const int tid = threadIdx.x, lane = tid & 63, w = tid >> 6;
  const int l16 = lane & 15, quad = lane >> 4;
  const size_t m0 = (size_t)blockIdx.x * 64;
  const short* qx  = (const short*)(p.ws + OFF_QXBF);
  const short* ew1 = (const short*)(p.ws + OFF_EW1);
  const short* ew2 = (const short*)(p.ws + OFF_EW2);
  const short* ew3 = (const short*)(p.ws + OFF_EW3);
  for (int nc = 0; nc < 2; ++nc) {
    f32x4 acc[4][4] = {};
    for (int kt = 0; kt < 4; ++kt) {
      bf16x8 bw[4];
#pragma unroll
      for (int i = 0; i < 4; ++i) {
        const int nt = w * 8 + nc * 4 + i;
        bw[i] = ldfrag(ew1 + ((size_t)(nt * 4 + kt) * 64 + lane) * 8);
      }
#pragma unroll
      for (int mt = 0; mt < 4; ++mt) {
        bf16x8 af = ldfrag(qx + (m0 + mt * 16 + l16) * 128 + kt * 32 + quad * 8);
#pragma unroll
        for (int i = 0; i < 4; ++i) acc[mt][i] = MFMA16(af, bw[i], acc[mt][i]);
      }
    }
#pragma unroll
    for (int mt = 0; mt < 4; ++mt)
#pragma unroll
      for (int i = 0; i < 4; ++i) {
        const int col = (w * 8 + nc * 4 + i) * 16 + l16;
        const float bias = p.eb1[col];
#pragma unroll
        for (int r = 0; r < 4; ++r) {
          const float v = acc[mt][i][r] + bias;
          h1[(mt * 16 + quad * 4 + r) * 520 + col] = f2bf(v > 0.f ? v : 0.f);
        }
      }
  }
  __syncthreads();
  for (int nc = 0; nc < 2; ++nc) {
    f32x4 acc[4][4] = {};
    for (int kt = 0; kt < 16; ++kt) {
      bf16x8 bw[4];
#pragma unroll
      for (int i = 0; i < 4; ++i) {
        const int nt = w * 8 + nc * 4 + i;
        bw[i] = ldfrag(ew2 + ((size_t)(nt * 16 + kt) * 64 + lane) * 8);
      }
#pragma unroll
      for (int mt = 0; mt < 4; ++mt) {
        bf16x8 af = ldfrag(h1 + (mt * 16 + l16) * 520 + kt * 32 + quad * 8);
#pragma unroll
        for (int i = 0; i < 4; ++i) acc[mt][i] = MFMA16(af, bw[i], acc[mt][i]);
      }
    }
#pragma unroll
    for (int mt = 0; mt < 4; ++mt)
#pragma unroll
      for (int i = 0; i < 4; ++i) {
        const int col = (w * 8 + nc * 4 + i) * 16 + l16;
        const float bias = p.eb2[col];
#pragma unroll
        for (int r = 0; r < 4; ++r) {
          const float v = acc[mt][i][r] + bias;
          h2[(mt * 16 + quad * 4 + r) * 520 + col] = f2bf(v > 0.f ? v : 0.f);
        }
      }
  }
  __syncthreads();
  for (int nc = 0; nc < 2; ++nc) {
    f32x4 acc[4][4] = {};
    for (int kt = 0; kt < 16; ++kt) {
      bf16x8 bw[4];
#pragma unroll
      for (int i = 0; i < 4; ++i) {
        const int nt = w * 8 + nc * 4 + i;
        bw[i] = ldfrag(ew3 + ((size_t)(nt * 16 + kt) * 64 + lane) * 8);
      }
#pragma unroll
      for (int mt = 0; mt < 4; ++mt) {
        bf16x8 af = ldfrag(h2 + (mt * 16 + l16) * 520 + kt * 32 + quad * 8);
#pragma unroll
        for (int i = 0; i < 4; ++i) acc[mt][i] = MFMA16(af, bw[i], acc[mt][i]);
      }
    }
#pragma unroll
    for (int mt = 0; mt < 4; ++mt)
#pragma unroll
      for (int i = 0; i < 4; ++i) {
        const int col = (w * 8 + nc * 4 + i) * 16 + l16;
        const float bias = p.eb3[col];
#pragma unroll
        for (int r = 0; r < 4; ++r) {
          const size_t m = m0 + mt * 16 + quad * 4 + r;
          const size_t b = m >> 10, tt2 = m & 1023;
          const float v = acc[mt][i][r] + bias;
          p.out[Y_O + (b << 19) + tt2 * 512 + col] = 1.f / (1.f + __expf(-v));
        }
      }
  }
}

extern "C" void kernel_launch(void* const* d_in, const int* in_sizes, int n_in,
                              void* d_out, int out_size, void* d_ws, size_t ws_size,
                              hipStream_t stream) {
  (void)in_sizes; (void)n_in; (void)out_size; (void)ws_size;
  P p;
  p.ws = (char*)d_ws; p.out = (float*)d_out;
  p.data = (const float*)d_in[0];
  p.eps_q = (const float*)d_in[1];
  p.eps_p = (const float*)d_in[2];
  p.Wih = (const float*)d_in[3]; p.Whh = (const float*)d_in[4];
  p.bih = (const float*)d_in[5]; p.bhh = (const float*)d_in[6];
  p.h0 = (const float*)d_in[7]; p.xq0 = (const float*)d_in[8]; p.x0 = (const float*)d_in[9];
  p.Wxh = (const float*)d_in[10]; p.bxh = (const float*)d_in[11];
  p.Whm = (const float*)d_in[12]; p.bhm = (const float*)d_in[13];
  p.Whl = (const float*)d_in[14]; p.bhl = (const float*)d_in[15];
  p.Wg1 = (const float*)d_in[16]; p.bg1 = (const float*)d_in[17];
  p.Wg2 = (const float*)d_in[18]; p.bg2 = (const float*)d_in[19];
  p.Wp1 = (const float*)d_in[20]; p.bp1 = (const float*)d_in[21];
  p.Wp2 = (const float*)d_in[22]; p.bp2 = (const float*)d_in[23];
  p.Wmu = (const float*)d_in[24]; p.bmu = (const float*)d_in[25];
  p.Wlv = (const float*)d_in[26]; p.blv = (const float*)d_in[27];
  p.eW1 = (const float*)d_in[28]; p.eb1 = (const float*)d_in[29];
  p.eW2 = (const float*)d_in[30]; p.eb2 = (const float*)d_in[31];
  p.eW3 = (const float*)d_in[32]; p.eb3 = (const float*)d_in[33];

  hipFuncSetAttribute(reinterpret_cast<const void*>(k_scan),
                      hipFuncAttributeMaxDynamicSharedMemorySize, SMEM_SCAN);
  hipFuncSetAttribute(reinterpret_cast<const void*>(k_emis),
                      hipFuncAttributeMaxDynamicSharedMemorySize, SMEM_EMIS);

  k_prep<<<dim3(2048), dim3(256), 0, stream>>>(p);
  k_scan<<<dim3(72), dim3(512), SMEM_SCAN, stream>>>(p);
  k_emis<<<dim3(1024), dim3(256), SMEM_EMIS, stream>>>(p);
}

// Round 6
// 11989.927 us; speedup vs baseline: 2.7707x; 1.0837x over previous
//
#include <hip/hip_runtime.h>
#include <stdint.h>

typedef __bf16 bf16x8 __attribute__((ext_vector_type(8)));
typedef short  s16x8  __attribute__((ext_vector_type(8)));
typedef float  f32x4  __attribute__((ext_vector_type(4)));

#define MFMA16(a, b, c) __builtin_amdgcn_mfma_f32_16x16x32_bf16((a), (b), (c), 0, 0, 0)

// ---------------- workspace layout (bytes) ----------------
#define OFF_X      0ull          // (T,64,512) bf16: xp, overwritten by h (history)
#define OFF_QXBF   67108864ull   // (B,T,128) bf16 copy of q_x for emission
#define OFF_WIH    83886080ull
#define OFF_WHH    84410368ull
#define OFF_WXH    84934656ull
#define OFF_WICAT  85065728ull   // [Whm|Whl] interleaved 64-col blocks, N=256
#define OFF_W1CAT  85327872ull   // [Wg1|Wp1], N=1024
#define OFF_WG2    85590016ull
#define OFF_WP2    85721088ull
#define OFF_WMU    85852160ull
#define OFF_WLV    85884928ull
#define OFF_EW1    85917696ull
#define OFF_EW2    86048768ull
#define OFF_EW3    86573056ull
#define OFF_B1CAT  87097344ull   // fp32 [1024]
#define OFF_BICAT  87101440ull   // fp32 [256]

// ---------------- d_out offsets (floats) ----------------
#define QX_O  0ull
#define QMU_O 8388608ull
#define QLV_O 16777216ull
#define PX_O  25165824ull
#define PMU_O 33554432ull
#define PLV_O 41943040ull
#define Y_O   50331648ull

#define SMEM_SCAN 131072
#define SMEM_EMIS 133120

struct P {
  char* ws; float* out;
  const float *data, *eps_q, *eps_p;
  const float *Wih, *Whh, *bih, *bhh, *h0, *xq0, *x0;
  const float *Wxh, *bxh, *Whm, *bhm, *Whl, *bhl;
  const float *Wg1, *bg1, *Wg2, *bg2, *Wp1, *bp1, *Wp2, *bp2, *Wmu, *bmu, *Wlv, *blv;
  const float *eW1, *eb1, *eW2, *eb2, *eW3, *eb3;
};

__device__ __forceinline__ short f2bf(float f) {
  union { float f; uint32_t u; } v; v.f = f;
  uint32_t r = (v.u + 0x7FFFu + ((v.u >> 16) & 1u)) >> 16;
  return (short)(uint16_t)r;
}
__device__ __forceinline__ float bf2f(short s) {
  union { uint32_t u; float f; } v; v.u = ((uint32_t)(uint16_t)s) << 16;
  return v.f;
}
__device__ __forceinline__ bf16x8 ldfrag(const short* pp) { return *(const bf16x8*)pp; }
__device__ __forceinline__ bf16x8 cvt8p(const float* pp) {
  bf16x8 r;
#pragma unroll
  for (int i = 0; i < 8; ++i) r[i] = (__bf16)pp[i];
  return r;
}
__device__ __forceinline__ bf16x8 relu8(bf16x8 a) {
  s16x8 s = __builtin_bit_cast(s16x8, a);
#pragma unroll
  for (int i = 0; i < 8; ++i) s[i] = (s[i] < 0) ? (short)0 : s[i];
  return __builtin_bit_cast(bf16x8, s);
}
__device__ __forceinline__ void relfence() {
  asm volatile("s_waitcnt vmcnt(0)" ::: "memory");
}
// LDS-only barrier: orders ds ops across the WG WITHOUT draining vmcnt.
__device__ __forceinline__ void barrier_lgkm() {
  __builtin_amdgcn_sched_barrier(0);
  asm volatile("s_waitcnt lgkmcnt(0)" ::: "memory");
  __builtin_amdgcn_s_barrier();
  __builtin_amdgcn_sched_barrier(0);
}

// pack W (K x N, row-major fp32) into MFMA-B fragment order:
// dst[((nt*KT+kt)*64+lane)*8+j] = W[kt*32+(lane>>4)*8+j][nt*16+(lane&15)]
__device__ __forceinline__ void pack_w(short* dst, const float* src, int KT, int N, int idx) {
  int tile = idx >> 9, rem = idx & 511;
  int lane = rem >> 3, j = rem & 7;
  int nt = tile / KT, kt = tile - nt * KT;
  int k = kt * 32 + ((lane >> 4) << 3) + j, n = (nt << 4) + (lane & 15);
  dst[idx] = f2bf(src[(int64_t)k * N + n]);
}

__global__ void __launch_bounds__(256) k_prep(P p) {
  char* ws = p.ws;
  const int64_t total = 1606912;
  for (int64_t i = (int64_t)blockIdx.x * 256 + threadIdx.x; i < total;
       i += (int64_t)gridDim.x * 256) {
    int64_t r = i;
    if (r < 262144) { pack_w((short*)(ws + OFF_WIH), p.Wih, 16, 512, (int)r); continue; }
    r -= 262144;
    if (r < 262144) { pack_w((short*)(ws + OFF_WHH), p.Whh, 16, 512, (int)r); continue; }
    r -= 262144;
    if (r < 65536) { pack_w((short*)(ws + OFF_WXH), p.Wxh, 4, 512, (int)r); continue; }
    r -= 65536;
    if (r < 131072) {  // Wicat
      int idx = (int)r;
      int tile = idx >> 9, rem = idx & 511, lane = rem >> 3, jj = rem & 7;
      int nt = tile >> 4, kt = tile & 15;
      int k = kt * 32 + ((lane >> 4) << 3) + jj, ccol = (nt << 4) + (lane & 15);
      int pair = ccol >> 7, within = ccol & 127, sub = within >> 6;
      int col = (within & 63) + (pair << 6);
      const float* s = sub ? p.Whl : p.Whm;
      ((short*)(ws + OFF_WICAT))[idx] = f2bf(s[(int64_t)k * 128 + col]);
      continue;
    }
    r -= 131072;
    if (r < 131072) {  // W1cat = [Wg1|Wp1]
      int idx = (int)r;
      int tile = idx >> 9, rem = idx & 511, lane = rem >> 3, jj = rem & 7;
      int nt = tile >> 2, kt = tile & 3;
      int k = kt * 32 + ((lane >> 4) << 3) + jj, ccol = (nt << 4) + (lane & 15);
      const float* s = (ccol < 512) ? p.Wg1 : p.Wp1;
      ((short*)(ws + OFF_W1CAT))[idx] = f2bf(s[(int64_t)k * 512 + (ccol & 511)]);
      continue;
    }
    r -= 131072;
    if (r < 65536) { pack_w((short*)(ws + OFF_WG2), p.Wg2, 16, 128, (int)r); continue; }
    r -= 65536;
    if (r < 65536) { pack_w((short*)(ws + OFF_WP2), p.Wp2, 16, 128, (int)r); continue; }
    r -= 65536;
    if (r < 16384) { pack_w((short*)(ws + OFF_WMU), p.Wmu, 4, 128, (int)r); continue; }
    r -= 16384;
    if (r < 16384) { pack_w((short*)(ws + OFF_WLV), p.Wlv, 4, 128, (int)r); continue; }
    r -= 16384;
    if (r < 65536) { pack_w((short*)(ws + OFF_EW1), p.eW1, 4, 512, (int)r); continue; }
    r -= 65536;
    if (r < 262144) { pack_w((short*)(ws + OFF_EW2), p.eW2, 16, 512, (int)r); continue; }
    r -= 262144;
    if (r < 262144) { pack_w((short*)(ws + OFF_EW3), p.eW3, 16, 512, (int)r); continue; }
    r -= 262144;
    if (r < 1024) { ((float*)(ws + OFF_B1CAT))[r] = (r < 512) ? p.bg1[r] : p.bp1[r - 512]; continue; }
    r -= 1024;
    if (r < 256) {
      int ccol = (int)r; int pair = ccol >> 7, within = ccol & 127, sub = within >> 6;
      int col = (within & 63) + (pair << 6);
      ((float*)(ws + OFF_BICAT))[ccol] = sub ? p.bhl[col] : p.bhm[col];
      continue;
    }
  }
}

// =====================================================================
// xproj: xp[t] = data[:, 1023-t, :] @ Wih + bih + bhh  (standalone GEMM,
// no dependencies, no flags). 512 WGs x 256 threads; WG (s, t0) covers
// nt slice s and times t = t0 + 64*tt.
// =====================================================================
__global__ void __launch_bounds__(256) k_xproj(P p) {
  char* ws = p.ws;
  const int tid = threadIdx.x;
  const int lane = tid & 63, w = tid >> 6;
  const int l16 = lane & 15, quad = lane >> 4;
  const int s = blockIdx.x & 7, t0 = blockIdx.x >> 3;
  short* Xb = (short*)(ws + OFF_X);
  const short* wih = (const short*)(ws + OFF_WIH);
  for (int tt = 0; tt < 16; ++tt) {
    const int t = t0 + (tt << 6);
    const int tsrc = 1023 - t;
    const float* arow = p.data + ((size_t)(w * 16 + l16) * 1024 + tsrc) * 512 + quad * 8;
    f32x4 acc[4] = {};
    for (int kt = 0; kt < 16; ++kt) {
      bf16x8 af = cvt8p(arow + kt * 32);
#pragma unroll
      for (int i = 0; i < 4; ++i) {
        const int nt = s * 4 + i;
        bf16x8 bw = ldfrag(wih + ((size_t)(nt * 16 + kt) * 64 + lane) * 8);
        acc[i] = MFMA16(af, bw, acc[i]);
      }
    }
    short* xrow = Xb + (size_t)t * 32768;
#pragma unroll
    for (int i = 0; i < 4; ++i) {
      const int col = (s * 4 + i) * 16 + l16;
      const float bias = p.bih[col] + p.bhh[col];
#pragma unroll
      for (int r = 0; r < 4; ++r) {
        const int row = w * 16 + quad * 4 + r;
        xrow[(size_t)row * 512 + col] = f2bf(acc[i][r] + bias);
      }
    }
  }
}

// =====================================================================
// persistent scan kernel: 8 WGs x 512 threads, ZERO cross-WG traffic.
//   [0,4): RNN crew (1 WG/group; Whh 13kt regs + 3kt LDS, h dbuf LDS)
//          -> re-roles to zero-hop inf crew
//   [4,8): gen crew (1 WG/group; W1cat regs, Wg2+Wp2 streamed, Wmu/Wlv LDS)
// amdgpu_waves_per_eu(2,2) pins 2 waves/EU -> 256 VGPR/wave so the
// register-resident weights actually stay in registers.
// =====================================================================
__global__ void __launch_bounds__(512)
__attribute__((amdgpu_waves_per_eu(2, 2))) k_scan(P p) {
  extern __shared__ char smem[];
  char* ws = p.ws;
  const int tid = threadIdx.x;
  const int lane = tid & 63, w = tid >> 6;
  const int l16 = lane & 15, quad = lane >> 4;
  const int wg = blockIdx.x;

  short* Xb   = (short*)(ws + OFF_X);
  short* qxbf = (short*)(ws + OFF_QXBF);

  if (wg < 4) {
    // ---------------- RNN crew: one WG per group, zero hops ----------
    const int g = wg;
    short* whh_l = (short*)smem;            // kt 13..15 frags, 96 KB
    char* hbuf = smem + 98304;              // [2][16][512] bf16 swizzled
    {
      const float4* src4 = (const float4*)(ws + OFF_WHH);
      float4* dst4 = (float4*)smem;
      for (int i2 = tid; i2 < 6144; i2 += 512) {
        const int blk = i2 >> 6, wi = i2 & 63;
        const int nt = blk / 3, kk = blk - nt * 3;
        dst4[(size_t)blk * 64 + wi] = src4[(size_t)(nt * 16 + 13 + kk) * 64 + wi];
      }
    }
    const short* whh = (const short*)(ws + OFF_WHH);
    bf16x8 wb[4][13];
#pragma unroll
    for (int i = 0; i < 4; ++i) {
      const int nt = w * 4 + i;
#pragma unroll
      for (int kt = 0; kt < 13; ++kt)
        wb[i][kt] = ldfrag(whh + ((size_t)(nt * 16 + kt) * 64 + lane) * 8);
    }
    __syncthreads();
    // xp(0) preload (plain loads; k_xproj already finished)
    short xv[4][4];
#pragma unroll
    for (int i = 0; i < 4; ++i) {
      const int col = (w * 4 + i) * 16 + l16;
#pragma unroll
      for (int r = 0; r < 4; ++r)
        xv[i][r] = Xb[(size_t)(g * 16 + quad * 4 + r) * 512 + col];
    }
    // -------- t = 0 peeled --------
    {
      f32x4 acc[4] = {};
#pragma unroll
      for (int c = 0; c < 8; ++c) {
        bf16x8 a2[2];
#pragma unroll
        for (int k2 = 0; k2 < 2; ++k2) a2[k2] = cvt8p(p.h0 + (c * 2 + k2) * 32 + quad * 8);
#pragma unroll
        for (int k2 = 0; k2 < 2; ++k2) {
          const int kt = c * 2 + k2;
#pragma unroll
          for (int i = 0; i < 4; ++i) {
            bf16x8 bw = (kt < 13)
                ? wb[i][kt]
                : ldfrag(whh_l + ((size_t)((w * 4 + i) * 3 + (kt - 13)) * 64 + lane) * 8);
            acc[i] = MFMA16(a2[k2], bw, acc[i]);
          }
        }
      }
      char* hw = hbuf;  // buffer 0
#pragma unroll
      for (int i = 0; i < 4; ++i) {
        const int col = (w * 4 + i) * 16 + l16;
#pragma unroll
        for (int r = 0; r < 4; ++r) {
          const int row = quad * 4 + r;
          float h = acc[i][r] + bf2f(xv[i][r]);
          const short hv = f2bf(h > 0.f ? h : 0.f);
          *(short*)(hw + row * 1024 + ((col * 2) ^ ((row & 7) << 4))) = hv;
          Xb[(size_t)(g * 16 + row) * 512 + col] = hv;
        }
      }
      // prefetch xp(1)
      const short* xn = Xb + 32768;
#pragma unroll
      for (int i = 0; i < 4; ++i) {
        const int col = (w * 4 + i) * 16 + l16;
#pragma unroll
        for (int r = 0; r < 4; ++r)
          xv[i][r] = xn[(size_t)(g * 16 + quad * 4 + r) * 512 + col];
      }
      barrier_lgkm();
    }
    // -------- t = 1..1023 --------
    for (int t = 1; t < 1024; ++t) {
      const char* hb = hbuf + ((t - 1) & 1) * 16384;
      f32x4 acc[4] = {};
#pragma unroll
      for (int c = 0; c < 8; ++c) {
        bf16x8 a2[2];
#pragma unroll
        for (int k2 = 0; k2 < 2; ++k2) {
          const int kt = c * 2 + k2;
          a2[k2] = ldfrag((const short*)(hb + l16 * 1024 +
                     ((kt * 64 + quad * 16) ^ ((l16 & 7) << 4))));
        }
#pragma unroll
        for (int k2 = 0; k2 < 2; ++k2) {
          const int kt = c * 2 + k2;
#pragma unroll
          for (int i = 0; i < 4; ++i) {
            bf16x8 bw = (kt < 13)
                ? wb[i][kt]
                : ldfrag(whh_l + ((size_t)((w * 4 + i) * 3 + (kt - 13)) * 64 + lane) * 8);
            acc[i] = MFMA16(a2[k2], bw, acc[i]);
          }
        }
      }
      char* hw = hbuf + (t & 1) * 16384;
      short* xrow = Xb + (size_t)t * 32768;
#pragma unroll
      for (int i = 0; i < 4; ++i) {
        const int col = (w * 4 + i) * 16 + l16;
#pragma unroll
        for (int r = 0; r < 4; ++r) {
          const int row = quad * 4 + r;
          float h = acc[i][r] + bf2f(xv[i][r]);
          const short hv = f2bf(h > 0.f ? h : 0.f);
          *(short*)(hw + row * 1024 + ((col * 2) ^ ((row & 7) << 4))) = hv;
          xrow[(size_t)(g * 16 + row) * 512 + col] = hv;
        }
      }
      if (t < 1023) {
        const short* xn = Xb + (size_t)(t + 1) * 32768;
#pragma unroll
        for (int i = 0; i < 4; ++i) {
          const int col = (w * 4 + i) * 16 + l16;
#pragma unroll
          for (int r = 0; r < 4; ++r)
            xv[i][r] = xn[(size_t)(g * 16 + quad * 4 + r) * 512 + col];
        }
      }
      barrier_lgkm();
    }
    // ---------------- re-role: zero-hop inf crew ----------------
    relfence();
    __syncthreads();
    const int g2 = g;
    char* hcs = smem;                     // [16][512] bf16 swz
    char* xqs = smem + 16384;             // [16][128] bf16 swz
    float* scr = (float*)(smem + 20480);  // [2][16][128] f32
    const short* wxh = (const short*)(ws + OFF_WXH);
    const short* wicat = (const short*)(ws + OFF_WICAT);
    const float* bicat = (const float*)(ws + OFF_BICAT);
    bf16x8 wa[4][4];
    float bx[4];
#pragma unroll
    for (int i = 0; i < 4; ++i) {
      const int nt = w * 4 + i;
#pragma unroll
      for (int kt = 0; kt < 4; ++kt)
        wa[i][kt] = ldfrag(wxh + ((size_t)(nt * 4 + kt) * 64 + lane) * 8);
      bx[i] = p.bxh[nt * 16 + l16];
    }
    bf16x8 wbv[2][16];
    float bias2[2];
#pragma unroll
    for (int i = 0; i < 2; ++i) {
      const int nt = w * 2 + i;
#pragma unroll
      for (int kt = 0; kt < 16; ++kt)
        wbv[i][kt] = ldfrag(wicat + ((size_t)(nt * 16 + kt) * 64 + lane) * 8);
      bias2[i] = bicat[nt * 16 + l16];
    }
    for (int t = 0; t < 1024; ++t) {
      // rnn_out + eps_q loads issued at step top (plain, latency overlapped)
      short rv[4][4];
      const short* rsrc = Xb + (size_t)(1023 - t) * 32768;
#pragma unroll
      for (int i = 0; i < 4; ++i) {
        const int ng = (w * 4 + i) * 16 + l16;
#pragma unroll
        for (int r = 0; r < 4; ++r)
          rv[i][r] = rsrc[(size_t)(g2 * 16 + quad * 4 + r) * 512 + ng];
      }
      float ev[4];
#pragma unroll
      for (int q2 = 0; q2 < 4; ++q2) {
        const int idx = tid + q2 * 512;
        const int row = idx >> 7, cl = idx & 127;
        ev[q2] = p.eps_q[((size_t)t * 64 + g2 * 16 + row) * 128 + cl];
      }
      // GEMM1: x_prev @ Wxh
      bf16x8 af1[4];
      if (t == 0) {
#pragma unroll
        for (int kt = 0; kt < 4; ++kt) af1[kt] = cvt8p(p.xq0 + kt * 32 + quad * 8);
      } else {
#pragma unroll
        for (int kt = 0; kt < 4; ++kt)
          af1[kt] = ldfrag((const short*)(xqs + l16 * 256 +
                     ((kt * 64 + quad * 16) ^ ((l16 & 7) << 4))));
      }
      f32x4 acc1[4] = {};
#pragma unroll
      for (int kt = 0; kt < 4; ++kt)
#pragma unroll
        for (int i = 0; i < 4; ++i) acc1[i] = MFMA16(af1[kt], wa[i][kt], acc1[i]);
#pragma unroll
      for (int i = 0; i < 4; ++i) {
        const int ng = (w * 4 + i) * 16 + l16;
#pragma unroll
        for (int r = 0; r < 4; ++r) {
          const int row = quad * 4 + r;
          const float u = acc1[i][r] + bx[i];
          const float e = __expf(2.f * u);
          const float th = 1.f - 2.f / (e + 1.f);
          const float hcv = 0.5f * (th + bf2f(rv[i][r]));
          *(short*)(hcs + row * 1024 + ((ng * 2) ^ ((row & 7) << 4))) = f2bf(hcv);
        }
      }
      barrier_lgkm();
      // GEMM2: h_c @ Wicat
      f32x4 acc2[2] = {};
#pragma unroll
      for (int c = 0; c < 4; ++c) {
        bf16x8 a4[4];
#pragma unroll
        for (int k2 = 0; k2 < 4; ++k2) {
          const int kt = c * 4 + k2;
          a4[k2] = ldfrag((const short*)(hcs + l16 * 1024 +
                     ((kt * 64 + quad * 16) ^ ((l16 & 7) << 4))));
        }
#pragma unroll
        for (int k2 = 0; k2 < 4; ++k2)
#pragma unroll
          for (int i = 0; i < 2; ++i) acc2[i] = MFMA16(a4[k2], wbv[i][c * 4 + k2], acc2[i]);
      }
#pragma unroll
      for (int i = 0; i < 2; ++i) {
        const int catcol = (w * 2 + i) * 16 + l16;
        const int within = catcol & 127, sub = within >> 6;
        const int col = (within & 63) + ((catcol >> 7) << 6);
        float* dbase = p.out + (sub ? QLV_O : QMU_O);
#pragma unroll
        for (int r = 0; r < 4; ++r) {
          const int row = quad * 4 + r;
          const float v = acc2[i][r] + bias2[i];
          dbase[(size_t)(g2 * 16 + row) * 131072 + (size_t)t * 128 + col] = v;
          scr[(sub * 16 + row) * 128 + col] = v;
        }
      }
      barrier_lgkm();
      // sample
#pragma unroll
      for (int q2 = 0; q2 < 4; ++q2) {
        const int idx = tid + q2 * 512;
        const int row = idx >> 7, cl = idx & 127;
        const int b = g2 * 16 + row;
        const float m = scr[row * 128 + cl], l = scr[(16 + row) * 128 + cl];
        const float xvv = m + ev[q2] * __expf(0.5f * l);
        p.out[QX_O + (size_t)b * 131072 + (size_t)t * 128 + cl] = xvv;
        const short xb = f2bf(xvv);
        qxbf[((size_t)b * 1024 + t) * 128 + cl] = xb;
        *(short*)(xqs + row * 256 + ((cl * 2) ^ ((row & 7) << 4))) = xb;
      }
      barrier_lgkm();
    }
    return;
  }

  // ---------------- gen crew: one WG per group, zero hops ----------------
  {
    const int g3 = wg - 4;
    short* ldsWmu = (short*)smem;              // 32 KB frag-order
    short* ldsWlv = (short*)(smem + 32768);    // 32 KB
    char* xls  = smem + 65536;                 // [16][128] bf16 swz
    char* u1ls = smem + 69632;                 // [16][1024] bf16 swz
    char* pmls = smem + 102400;                // [16][128] bf16 swz
    {
      const float4* s1 = (const float4*)(ws + OFF_WMU);
      const float4* s2 = (const float4*)(ws + OFF_WLV);
      float4* d1 = (float4*)smem;
      float4* d2 = (float4*)(smem + 32768);
      for (int i2 = tid; i2 < 2048; i2 += 512) { d1[i2] = s1[i2]; d2[i2] = s2[i2]; }
    }
    const short* w1cat = (const short*)(ws + OFF_W1CAT);
    const float* b1cat = (const float*)(ws + OFF_B1CAT);
    const short* wp2g = (const short*)(ws + OFF_WP2);
    const short* wg2g = (const short*)(ws + OFF_WG2);
    bf16x8 w1[8][4];
    float b1[8];
#pragma unroll
    for (int i = 0; i < 8; ++i) {
      const int nt = w * 8 + i;
#pragma unroll
      for (int kt = 0; kt < 4; ++kt)
        w1[i][kt] = ldfrag(w1cat + ((size_t)(nt * 4 + kt) * 64 + lane) * 8);
      b1[i] = b1cat[nt * 16 + l16];
    }
    const int colw = w * 16 + l16;
    const float bpv = p.bp2[colw], bgv = p.bg2[colw], bmv = p.bmu[colw], blvv = p.blv[colw];
    __syncthreads();
    for (int t = 0; t < 1024; ++t) {
      float ep[4];
#pragma unroll
      for (int r = 0; r < 4; ++r)
        ep[r] = p.eps_p[((size_t)t * 64 + g3 * 16 + quad * 4 + r) * 128 + colw];
      // P1: u1 = relu(x @ [Wg1|Wp1] + b1)
      bf16x8 ax[4];
      if (t == 0) {
#pragma unroll
        for (int kt = 0; kt < 4; ++kt) ax[kt] = cvt8p(p.x0 + kt * 32 + quad * 8);
      } else {
#pragma unroll
        for (int kt = 0; kt < 4; ++kt)
          ax[kt] = ldfrag((const short*)(xls + l16 * 256 +
                     ((kt * 64 + quad * 16) ^ ((l16 & 7) << 4))));
      }
#pragma unroll
      for (int hf = 0; hf < 2; ++hf) {
        f32x4 a1[4] = {};
#pragma unroll
        for (int kt = 0; kt < 4; ++kt)
#pragma unroll
          for (int i = 0; i < 4; ++i) a1[i] = MFMA16(ax[kt], w1[hf * 4 + i][kt], a1[i]);
#pragma unroll
        for (int i = 0; i < 4; ++i) {
          const int c1 = (w * 8 + hf * 4 + i) * 16 + l16;
#pragma unroll
          for (int r = 0; r < 4; ++r) {
            const int row = quad * 4 + r;
            const float u = a1[i][r] + b1[hf * 4 + i];
            *(short*)(u1ls + row * 2048 + ((c1 * 2) ^ ((row & 7) << 4))) = f2bf(u > 0.f ? u : 0.f);
          }
        }
      }
      barrier_lgkm();
      // P2: pm (Wp2 streamed), gate (Wg2 streamed), xmu (LDS Wmu)
      f32x4 apm = {}, ag = {}, axm = {};
#pragma unroll
      for (int c = 0; c < 8; ++c) {
        bf16x8 bpf[2], bgf[2];
#pragma unroll
        for (int k2 = 0; k2 < 2; ++k2) {
          bpf[k2] = ldfrag(wp2g + ((size_t)(w * 16 + c * 2 + k2) * 64 + lane) * 8);
          bgf[k2] = ldfrag(wg2g + ((size_t)(w * 16 + c * 2 + k2) * 64 + lane) * 8);
        }
        bf16x8 aup[2], aug[2];
#pragma unroll
        for (int k2 = 0; k2 < 2; ++k2) {
          const int kt = c * 2 + k2;
          aup[k2] = ldfrag((const short*)(u1ls + l16 * 2048 +
                      ((1024 + kt * 64 + quad * 16) ^ ((l16 & 7) << 4))));
          aug[k2] = ldfrag((const short*)(u1ls + l16 * 2048 +
                      ((kt * 64 + quad * 16) ^ ((l16 & 7) << 4))));
        }
#pragma unroll
        for (int k2 = 0; k2 < 2; ++k2) {
          apm = MFMA16(aup[k2], bpf[k2], apm);
          ag  = MFMA16(aug[k2], bgf[k2], ag);
        }
      }
#pragma unroll
      for (int kt = 0; kt < 4; ++kt) {
        bf16x8 bw = ldfrag(ldsWmu + ((size_t)(w * 4 + kt) * 64 + lane) * 8);
        axm = MFMA16(ax[kt], bw, axm);
      }
      float pmv[4];
#pragma unroll
      for (int r = 0; r < 4; ++r) {
        const int row = quad * 4 + r;
        pmv[r] = apm[r] + bpv;
        *(short*)(pmls + row * 256 + ((colw * 2) ^ ((row & 7) << 4))) = f2bf(pmv[r]);
      }
      barrier_lgkm();
      // P3: lv = relu(pm)@Wlv; mu; sample; outputs
      bf16x8 apf[4];
#pragma unroll
      for (int kt = 0; kt < 4; ++kt)
        apf[kt] = relu8(ldfrag((const short*)(pmls + l16 * 256 +
                    ((kt * 64 + quad * 16) ^ ((l16 & 7) << 4)))));
      f32x4 alv = {};
#pragma unroll
      for (int kt = 0; kt < 4; ++kt) {
        bf16x8 bw = ldfrag(ldsWlv + ((size_t)(w * 4 + kt) * 64 + lane) * 8);
        alv = MFMA16(apf[kt], bw, alv);
      }
#pragma unroll
      for (int r = 0; r < 4; ++r) {
        const int row = quad * 4 + r, b = g3 * 16 + row;
        const float lv = alv[r] + blvv;
        const float gv = 1.f / (1.f + __expf(-(ag[r] + bgv)));
        const float xmv = axm[r] + bmv;
        const float mu = (1.f - gv) * xmv + gv * pmv[r];
        const float xvv = mu + ep[r] * __expf(0.5f * lv);
        *(short*)(xls + row * 256 + ((colw * 2) ^ ((row & 7) << 4))) = f2bf(xvv);
        p.out[PMU_O + (size_t)b * 131072 + (size_t)t * 128 + colw] = mu;
        p.out[PLV_O + (size_t)b * 131072 + (size_t)t * 128 + colw] = lv;
        p.out[PX_O  + (size_t)b * 131072 + (size_t)t * 128 + colw] = xvv;
      }
      barrier_lgkm();
    }
    return;
  }
}

// =====================================================================
// fused emission MLP: y = sigmoid(relu(relu(qx@W1+b1)@W2+b2)@W3+b3)
// =====================================================================
__global__ void __launch_bounds__(256) k_emis(P p) {
  extern __shared__ char smem[];
  short* h1 = (short*)smem;            // [64][520]
  short* h2 = (short*)(smem + 66560);  // [64][520]
  const int tid = threadIdx.x, lane = tid & 63, w = tid >> 6;
  const int l16 = lane & 15, quad = lane >> 4;
  const size_t m0 = (size_t)blockIdx.x * 64;
  const short* qx  = (const short*)(p.ws + OFF_QXBF);
  const short* ew1 = (const short*)(p.ws + OFF_EW1);
  const short* ew2 = (const short*)(p.ws + OFF_EW2);
  const short* ew3 = (const short*)(p.ws + OFF_EW3);
  for (int nc = 0; nc < 2; ++nc) {
    f32x4 acc[4][4] = {};
    for (int kt = 0; kt < 4; ++kt) {
      bf16x8 bw[4];
#pragma unroll
      for (int i = 0; i < 4; ++i) {
        const int nt = w * 8 + nc * 4 + i;
        bw[i] = ldfrag(ew1 + ((size_t)(nt * 4 + kt) * 64 + lane) * 8);
      }
#pragma unroll
      for (int mt = 0; mt < 4; ++mt) {
        bf16x8 af = ldfrag(qx + (m0 + mt * 16 + l16) * 128 + kt * 32 + quad * 8);
#pragma unroll
        for (int i = 0; i < 4; ++i) acc[mt][i] = MFMA16(af, bw[i], acc[mt][i]);
      }
    }
#pragma unroll
    for (int mt = 0; mt < 4; ++mt)
#pragma unroll
      for (int i = 0; i < 4; ++i) {
        const int col = (w * 8 + nc * 4 + i) * 16 + l16;
        const float bias = p.eb1[col];
#pragma unroll
        for (int r = 0; r < 4; ++r) {
          const float v = acc[mt][i][r] + bias;
          h1[(mt * 16 + quad * 4 + r) * 520 + col] = f2bf(v > 0.f ? v : 0.f);
        }
      }
  }
  __syncthreads();
  for (int nc = 0; nc < 2; ++nc) {
    f32x4 acc[4][4] = {};
    for (int kt = 0; kt < 16; ++kt) {
      bf16x8 bw[4];
#pragma unroll
      for (int i = 0; i < 4; ++i) {
        const int nt = w * 8 + nc * 4 + i;
        bw[i] = ldfrag(ew2 + ((size_t)(nt * 16 + kt) * 64 + lane) * 8);
      }
#pragma unroll
      for (int mt = 0; mt < 4; ++mt) {
        bf16x8 af = ldfrag(h1 + (mt * 16 + l16) * 520 + kt * 32 + quad * 8);
#pragma unroll
        for (int i = 0; i < 4; ++i) acc[mt][i] = MFMA16(af, bw[i], acc[mt][i]);
      }
    }
#pragma unroll
    for (int mt = 0; mt < 4; ++mt)
#pragma unroll
      for (int i = 0; i < 4; ++i) {
        const int col = (w * 8 + nc * 4 + i) * 16 + l16;
        const float bias = p.eb2[col];
#pragma unroll
        for (int r = 0; r < 4; ++r) {
          const float v = acc[mt][i][r] + bias;
          h2[(mt * 16 + quad * 4 + r) * 520 + col] = f2bf(v > 0.f ? v : 0.f);
        }
      }
  }
  __syncthreads();
  for (int nc = 0; nc < 2; ++nc) {
    f32x4 acc[4][4] = {};
    for (int kt = 0; kt < 16; ++kt) {
      bf16x8 bw[4];
#pragma unroll
      for (int i = 0; i < 4; ++i) {
        const int nt = w * 8 + nc * 4 + i;
        bw[i] = ldfrag(ew3 + ((size_t)(nt * 16 + kt) * 64 + lane) * 8);
      }
#pragma unroll
      for (int mt = 0; mt < 4; ++mt) {
        bf16x8 af = ldfrag(h2 + (mt * 16 + l16) * 520 + kt * 32 + quad * 8);
#pragma unroll
        for (int i = 0; i < 4; ++i) acc[mt][i] = MFMA16(af, bw[i], acc[mt][i]);
      }
    }
#pragma unroll
    for (int mt = 0; mt < 4; ++mt)
#pragma unroll
      for (int i = 0; i < 4; ++i) {
        const int col = (w * 8 + nc * 4 + i) * 16 + l16;
        const float bias = p.eb3[col];
#pragma unroll
        for (int r = 0; r < 4; ++r) {
          const size_t m = m0 + mt * 16 + quad * 4 + r;
          const size_t b = m >> 10, tt2 = m & 1023;
          const float v = acc[mt][i][r] + bias;
          p.out[Y_O + (b << 19) + tt2 * 512 + col] = 1.f / (1.f + __expf(-v));
        }
      }
  }
}

extern "C" void kernel_launch(void* const* d_in, const int* in_sizes, int n_in,
                              void* d_out, int out_size, void* d_ws, size_t ws_size,
                              hipStream_t stream) {
  (void)in_sizes; (void)n_in; (void)out_size; (void)ws_size;
  P p;
  p.ws = (char*)d_ws; p.out = (float*)d_out;
  p.data = (const float*)d_in[0];
  p.eps_q = (const float*)d_in[1];
  p.eps_p = (const float*)d_in[2];
  p.Wih = (const float*)d_in[3]; p.Whh = (const float*)d_in[4];
  p.bih = (const float*)d_in[5]; p.bhh = (const float*)d_in[6];
  p.h0 = (const float*)d_in[7]; p.xq0 = (const float*)d_in[8]; p.x0 = (const float*)d_in[9];
  p.Wxh = (const float*)d_in[10]; p.bxh = (const float*)d_in[11];
  p.Whm = (const float*)d_in[12]; p.bhm = (const float*)d_in[13];
  p.Whl = (const float*)d_in[14]; p.bhl = (const float*)d_in[15];
  p.Wg1 = (const float*)d_in[16]; p.bg1 = (const float*)d_in[17];
  p.Wg2 = (const float*)d_in[18]; p.bg2 = (const float*)d_in[19];
  p.Wp1 = (const float*)d_in[20]; p.bp1 = (const float*)d_in[21];
  p.Wp2 = (const float*)d_in[22]; p.bp2 = (const float*)d_in[23];
  p.Wmu = (const float*)d_in[24]; p.bmu = (const float*)d_in[25];
  p.Wlv = (const float*)d_in[26]; p.blv = (const float*)d_in[27];
  p.eW1 = (const float*)d_in[28]; p.eb1 = (const float*)d_in[29];
  p.eW2 = (const float*)d_in[30]; p.eb2 = (const float*)d_in[31];
  p.eW3 = (const float*)d_in[32]; p.eb3 = (const float*)d_in[33];

  hipFuncSetAttribute(reinterpret_cast<const void*>(k_scan),
                      hipFuncAttributeMaxDynamicSharedMemorySize, SMEM_SCAN);
  hipFuncSetAttribute(reinterpret_cast<const void*>(k_emis),
                      hipFuncAttributeMaxDynamicSharedMemorySize, SMEM_EMIS);

  k_prep<<<dim3(2048), dim3(256), 0, stream>>>(p);
  k_xproj<<<dim3(512), dim3(256), 0, stream>>>(p);
  k_scan<<<dim3(8), dim3(512), SMEM_SCAN, stream>>>(p);
  k_emis<<<dim3(1024), dim3(256), SMEM_EMIS, stream>>>(p);
}